// Round 3
// baseline (681.193 us; speedup 1.0000x reference)
//
#include <hip/hip_runtime.h>

#define NN 20000
#define EE 320000
#define MPAD 20096   // NN padded to multiple of 128
#define MTILES 157   // ceil(NN/128)
#define DKB 128      // decoder partial blocks
#define DCH 9        // ceil(1025/128)

typedef unsigned short u16;
typedef unsigned int u32;
typedef __attribute__((ext_vector_type(8))) short short8;
typedef __attribute__((ext_vector_type(4))) float f32x4;

// ---------------- bf16 helpers ----------------
__device__ inline float bf16lo(u32 u) { return __uint_as_float(u << 16); }
__device__ inline float bf16hi(u32 u) { return __uint_as_float(u & 0xffff0000u); }
__device__ inline u16 f2b(float f) {
  u32 u = __float_as_uint(f);
  u += 0x7fffu + ((u >> 16) & 1u);
  return (u16)(u >> 16);
}
__device__ inline u32 pack2(float a, float b) {
  return (u32)f2b(a) | ((u32)f2b(b) << 16);
}

__device__ inline void gload16(const void* g, void* l) {
  __builtin_amdgcn_global_load_lds(
      (const __attribute__((address_space(1))) void*)g,
      (__attribute__((address_space(3))) void*)l, 16, 0, 0);
}

// ---------------- zero-init (int) ----------------
__global__ void k_zeroi(int* __restrict__ p, int n) {
  int i = blockIdx.x * blockDim.x + threadIdx.x;
  if (i < n) p[i] = 0;
}

// ---------------- fp32 -> bf16 cast (pairs) ----------------
__global__ void k_f2b2(const float* __restrict__ in, u16* __restrict__ out, int npairs) {
  for (int i = blockIdx.x * blockDim.x + threadIdx.x; i < npairs; i += gridDim.x * blockDim.x) {
    float2 v = *(const float2*)(in + 2 * i);
    ((u32*)out)[i] = pack2(v.x, v.y);
  }
}

// ---------------- all weight transposes in one launch ----------------
// W[K x N] fp32 -> WT[N x K] bf16, 5 matrices by blockIdx range
__global__ void k_wt_all(const float* __restrict__ W1, const float* __restrict__ W2,
                         const float* __restrict__ W3, const float* __restrict__ Wmu,
                         const float* __restrict__ Wlv,
                         u16* __restrict__ T1, u16* __restrict__ T2,
                         u16* __restrict__ T3, u16* __restrict__ Tmu,
                         u16* __restrict__ Tlv) {
  int b = blockIdx.x;
  const float* W; u16* T; int K, N;
  if (b < 2048)      { W = W1;  T = T1;  K = 512;  N = 1024; }
  else if (b < 4096) { W = W2;  T = T2;  K = 1024; N = 512;  b -= 2048; }
  else if (b < 4608) { W = W3;  T = T3;  K = 512;  N = 256;  b -= 4096; }
  else if (b < 5120) { W = Wmu; T = Tmu; K = 256;  N = 512;  b -= 4608; }
  else               { W = Wlv; T = Tlv; K = 256;  N = 512;  b -= 5120; }
  int kb = K >> 8;
  int n = b / kb;
  int k = (b % kb) * 256 + threadIdx.x;
  T[(size_t)n * K + k] = f2b(W[(size_t)k * N + n]);
}

// ---------------- CSR build: count / scan / fill ----------------
__global__ void k_count(const int* __restrict__ ei, int* __restrict__ counts) {
  int e = blockIdx.x * blockDim.x + threadIdx.x;
  if (e < EE) atomicAdd(counts + ei[EE + e], 1);
}

__global__ __launch_bounds__(256)
void k_scan(const int* __restrict__ counts, int* __restrict__ rowptr, int* __restrict__ cursor) {
  const int CHUNK = (NN + 255) / 256;
  int t = threadIdx.x;
  int lo = t * CHUNK, hi = min(lo + CHUNK, NN);
  int s = 0;
  for (int i = lo; i < hi; ++i) s += counts[i];
  __shared__ int tsum[256];
  tsum[t] = s;
  __syncthreads();
  if (t == 0) {
    int run = 0;
    for (int i = 0; i < 256; ++i) { int v = tsum[i]; tsum[i] = run; run += v; }
  }
  __syncthreads();
  int run = tsum[t];
  for (int i = lo; i < hi; ++i) {
    rowptr[i] = run;
    cursor[i] = run;
    run += counts[i];
  }
  if (t == 255) rowptr[NN] = EE;
}

__global__ void k_fill(const int* __restrict__ ei, const float* __restrict__ ew,
                       int* __restrict__ cursor, int* __restrict__ colsrc,
                       float* __restrict__ ecw) {
  int e = blockIdx.x * blockDim.x + threadIdx.x;
  if (e < EE) {
    int d = ei[EE + e];
    int pos = atomicAdd(cursor + d, 1);
    colsrc[pos] = ei[e];
    ecw[pos] = ew[e];
  }
}

__global__ void k_degcsr(const int* __restrict__ rowptr, const float* __restrict__ ecw,
                         float* __restrict__ dinv, float* __restrict__ dinv2) {
  int i = blockIdx.x * blockDim.x + threadIdx.x;
  if (i < NN) {
    float s = 0.f;
    for (int e = rowptr[i]; e < rowptr[i + 1]; ++e) s += ecw[e];
    float d = s + 1.0f;
    dinv[i] = rsqrtf(d);
    dinv2[i] = 1.0f / d;
  }
}

// ---------------- bf16 MFMA GEMM: C[M,N] = A[M,K] @ BT[N,K]^T (+bias) ----------------
template <bool STORE_BF16, bool HAS_BIAS>
__global__ __launch_bounds__(256)
void k_mfma(const u16* __restrict__ A, const u16* __restrict__ BT,
            const float* __restrict__ bias, void* __restrict__ C,
            int M, int K, int N) {
  __shared__ u16 Asm[128 * 32];
  __shared__ u16 Bsm[128 * 32];
  const int tid = threadIdx.x;
  const int m0 = blockIdx.x * 128;
  const int n0 = blockIdx.y * 128;
  const int lane = tid & 63;
  const int wave = tid >> 6;
  const int wm = (wave >> 1) * 64;
  const int wn = (wave & 1) * 64;
  const int qm = lane & 15;
  const int quad = lane >> 4;

  f32x4 acc[4][4];
#pragma unroll
  for (int i = 0; i < 4; ++i)
#pragma unroll
    for (int j = 0; j < 4; ++j) acc[i][j] = (f32x4){0.f, 0.f, 0.f, 0.f};

  for (int k0 = 0; k0 < K; k0 += 32) {
#pragma unroll
    for (int h = 0; h < 2; ++h) {
      int c = h * 256 + tid;
      int row = c >> 2, kc = c & 3;
      gload16(A + (size_t)(m0 + row) * K + k0 + kc * 8, Asm + c * 8);
      gload16(BT + (size_t)(n0 + row) * K + k0 + kc * 8, Bsm + c * 8);
    }
    __syncthreads();
    short8 af[4], bfr[4];
#pragma unroll
    for (int i = 0; i < 4; ++i)
      af[i] = *(const short8*)(Asm + (wm + i * 16 + qm) * 32 + quad * 8);
#pragma unroll
    for (int j = 0; j < 4; ++j)
      bfr[j] = *(const short8*)(Bsm + (wn + j * 16 + qm) * 32 + quad * 8);
#pragma unroll
    for (int i = 0; i < 4; ++i)
#pragma unroll
      for (int j = 0; j < 4; ++j)
        acc[i][j] = __builtin_amdgcn_mfma_f32_16x16x32_bf16(af[i], bfr[j], acc[i][j], 0, 0, 0);
    __syncthreads();
  }

#pragma unroll
  for (int i = 0; i < 4; ++i) {
#pragma unroll
    for (int r = 0; r < 4; ++r) {
      int row = m0 + wm + i * 16 + quad * 4 + r;
      if (row >= M) continue;
#pragma unroll
      for (int j = 0; j < 4; ++j) {
        int col = n0 + wn + j * 16 + qm;
        float v = acc[i][j][r];
        if (HAS_BIAS) v += bias[col];
        if (STORE_BF16) ((u16*)C)[(size_t)row * N + col] = f2b(v);
        else ((float*)C)[(size_t)row * N + col] = v;
      }
    }
  }
}

// ---------------- dual-head MFMA + fused z-pooling, coalesced LDS-transpose epilogue ----------------
__global__ __launch_bounds__(256)
void k_heads(const u16* __restrict__ A, const u16* __restrict__ BmuT,
             const u16* __restrict__ BlvT, const float* __restrict__ bmu,
             const float* __restrict__ blv, const float* __restrict__ eps,
             const float* __restrict__ beta_p, float* __restrict__ mu_out,
             float* __restrict__ lv_out, float* __restrict__ pmax,
             float* __restrict__ psum) {
  const int K = 256;
  __shared__ float smemf[8704];  // 34816 B, aliased across phases
  u16* Asm = (u16*)smemf;                    // [0, 8192)
  u16* Bmu = (u16*)((char*)smemf + 8192);    // [8192, 16384)
  u16* Blv = (u16*)((char*)smemf + 16384);   // [16384, 24576)
  float* stmu = smemf;                       // 32*132 floats = 16896 B
  float* stlv = smemf + 32 * 132;            // another 16896 B (total 33792)
  const int tid = threadIdx.x;
  const int m0 = blockIdx.x * 128;
  const int n0 = blockIdx.y * 128;
  const int lane = tid & 63;
  const int wave = tid >> 6;
  const int wn = (wave & 1) * 64;
  const int qm = lane & 15;
  const int quad = lane >> 4;

  f32x4 am[4][4], al[4][4];
#pragma unroll
  for (int i = 0; i < 4; ++i)
#pragma unroll
    for (int j = 0; j < 4; ++j) {
      am[i][j] = (f32x4){0.f, 0.f, 0.f, 0.f};
      al[i][j] = (f32x4){0.f, 0.f, 0.f, 0.f};
    }

  const int wm = (wave >> 1) * 64;
  for (int k0 = 0; k0 < K; k0 += 32) {
#pragma unroll
    for (int h = 0; h < 2; ++h) {
      int c = h * 256 + tid;
      int row = c >> 2, kc = c & 3;
      gload16(A + (size_t)(m0 + row) * K + k0 + kc * 8, Asm + c * 8);
      gload16(BmuT + (size_t)(n0 + row) * K + k0 + kc * 8, Bmu + c * 8);
      gload16(BlvT + (size_t)(n0 + row) * K + k0 + kc * 8, Blv + c * 8);
    }
    __syncthreads();
    short8 af[4], bm[4], bl[4];
#pragma unroll
    for (int i = 0; i < 4; ++i)
      af[i] = *(const short8*)(Asm + (wm + i * 16 + qm) * 32 + quad * 8);
#pragma unroll
    for (int j = 0; j < 4; ++j) {
      bm[j] = *(const short8*)(Bmu + (wn + j * 16 + qm) * 32 + quad * 8);
      bl[j] = *(const short8*)(Blv + (wn + j * 16 + qm) * 32 + quad * 8);
    }
#pragma unroll
    for (int i = 0; i < 4; ++i)
#pragma unroll
      for (int j = 0; j < 4; ++j) {
        am[i][j] = __builtin_amdgcn_mfma_f32_16x16x32_bf16(af[i], bm[j], am[i][j], 0, 0, 0);
        al[i][j] = __builtin_amdgcn_mfma_f32_16x16x32_bf16(af[i], bl[j], al[i][j], 0, 0, 0);
      }
    __syncthreads();
  }

  const float beta = beta_p[0];
  float biasm[4], biasl[4];
#pragma unroll
  for (int j = 0; j < 4; ++j) {
    int col = n0 + wn + j * 16 + qm;
    biasm[j] = bmu[col];
    biasl[j] = blv[col];
  }

  float zmax[16], zsum[16];
#pragma unroll
  for (int q = 0; q < 16; ++q) { zmax[q] = -3.4e38f; zsum[q] = 0.f; }
  const int lrow_r = tid >> 3;        // 0..31
  const int colb = (tid & 7) * 16;    // 0..112

  for (int c = 0; c < 4; ++c) {
    __syncthreads();
    if ((wave >> 1) == (c >> 1)) {
      int ibase = (c & 1) * 2;
#pragma unroll
      for (int ii = 0; ii < 2; ++ii) {
        int i = ibase + ii;
#pragma unroll
        for (int j = 0; j < 4; ++j) {
          int lcol = wn + j * 16 + qm;
#pragma unroll
          for (int r = 0; r < 4; ++r) {
            int lr = ii * 16 + quad * 4 + r;
            stmu[lr * 132 + lcol] = am[i][j][r] + biasm[j];
            stlv[lr * 132 + lcol] = al[i][j][r] + biasl[j];
          }
        }
      }
    }
    __syncthreads();
    int grow = m0 + c * 32 + lrow_r;
    if (grow < NN) {
#pragma unroll
      for (int q = 0; q < 4; ++q) {
        int lcol = colb + q * 4;
        float4 m4 = *(float4*)(stmu + lrow_r * 132 + lcol);
        float4 l4 = *(float4*)(stlv + lrow_r * 132 + lcol);
        size_t gidx = (size_t)grow * 512 + n0 + lcol;
        float4 e4 = *(const float4*)(eps + gidx);
        *(float4*)(mu_out + gidx) = m4;
        *(float4*)(lv_out + gidx) = l4;
        float z0 = m4.x + 0.01f * e4.x * expf(0.5f * beta * l4.x);
        float z1 = m4.y + 0.01f * e4.y * expf(0.5f * beta * l4.y);
        float z2 = m4.z + 0.01f * e4.z * expf(0.5f * beta * l4.z);
        float z3 = m4.w + 0.01f * e4.w * expf(0.5f * beta * l4.w);
        zmax[q * 4 + 0] = fmaxf(zmax[q * 4 + 0], z0); zsum[q * 4 + 0] += z0;
        zmax[q * 4 + 1] = fmaxf(zmax[q * 4 + 1], z1); zsum[q * 4 + 1] += z1;
        zmax[q * 4 + 2] = fmaxf(zmax[q * 4 + 2], z2); zsum[q * 4 + 2] += z2;
        zmax[q * 4 + 3] = fmaxf(zmax[q * 4 + 3], z3); zsum[q * 4 + 3] += z3;
      }
    }
  }

  __syncthreads();
  float* rbuf = smemf;  // 256*32 floats = 32768 B
#pragma unroll
  for (int q = 0; q < 16; ++q) {
    rbuf[tid * 32 + q] = zmax[q];
    rbuf[tid * 32 + 16 + q] = zsum[q];
  }
  __syncthreads();
  if (tid < 128) {
    int colgroup = tid >> 4, coff = tid & 15;
    float m = -3.4e38f, s = 0.f;
    for (int k = 0; k < 32; ++k) {
      int src = (k * 8 + colgroup) * 32;
      m = fmaxf(m, rbuf[src + coff]);
      s += rbuf[src + 16 + coff];
    }
    pmax[(size_t)blockIdx.x * 512 + n0 + tid] = m;
    psum[(size_t)blockIdx.x * 512 + n0 + tid] = s;
  }
}

// rz[1025] = [max-pool | mean-pool | y_target], reducing MTILES partials
__global__ void k_zred(const float* __restrict__ pmax, const float* __restrict__ psum,
                       const float* __restrict__ yt, float* __restrict__ rz) {
  int col = threadIdx.x;  // 512 threads
  float m = -3.4e38f, s = 0.f;
  for (int c = 0; c < MTILES; ++c) {
    m = fmaxf(m, pmax[(size_t)c * 512 + col]);
    s += psum[(size_t)c * 512 + col];
  }
  rz[col] = m;
  rz[512 + col] = s / (float)NN;
  if (col == 0) rz[1024] = yt[0];
}

// ---------------- fused CSR gather (bf16 in/out), vectorized: O = 4*NT ----------------
// Each thread owns 4 features via uint2 (8B) loads; 2-way edge unroll with
// dual accumulator sets for MLP.
template <int NT, bool PRE>
__global__ __launch_bounds__(NT)
void k_gatherv(const int* __restrict__ rowptr, const int* __restrict__ colsrc,
               const float* __restrict__ ecw, const float* __restrict__ dinv,
               const float* __restrict__ dinv2, const u16* __restrict__ xw,
               const float* __restrict__ bias, u16* __restrict__ h) {
  const int O = 4 * NT;
  const int row = blockIdx.x;
  const int tid = threadIdx.x;
  const float dv = dinv[row], dv2 = dinv2[row];
  uint2 u = ((const uint2*)(xw + (size_t)row * O))[tid];
  float a0 = dv2 * bf16lo(u.x), a1 = dv2 * bf16hi(u.x);
  float a2 = dv2 * bf16lo(u.y), a3 = dv2 * bf16hi(u.y);
  if (!PRE) {
    a0 += bias[4 * tid];     a1 += bias[4 * tid + 1];
    a2 += bias[4 * tid + 2]; a3 += bias[4 * tid + 3];
  }
  float c0 = 0.f, c1 = 0.f, c2 = 0.f, c3 = 0.f;

  __shared__ int s_src[NT];
  __shared__ float s_w[NT];
  const int e0 = rowptr[row], e1 = rowptr[row + 1];
  for (int base = e0; base < e1; base += NT) {
    int cnt = min(NT, e1 - base);
    __syncthreads();
    if (tid < cnt) {
      int s = colsrc[base + tid];
      s_src[tid] = s;
      s_w[tid] = dinv[s] * ecw[base + tid] * dv;
    }
    __syncthreads();
    int e = 0;
    for (; e + 2 <= cnt; e += 2) {
      float w0 = s_w[e], w1 = s_w[e + 1];
      uint2 v0 = ((const uint2*)(xw + (size_t)s_src[e] * O))[tid];
      uint2 v1 = ((const uint2*)(xw + (size_t)s_src[e + 1] * O))[tid];
      a0 += w0 * bf16lo(v0.x); a1 += w0 * bf16hi(v0.x);
      a2 += w0 * bf16lo(v0.y); a3 += w0 * bf16hi(v0.y);
      c0 += w1 * bf16lo(v1.x); c1 += w1 * bf16hi(v1.x);
      c2 += w1 * bf16lo(v1.y); c3 += w1 * bf16hi(v1.y);
    }
    if (e < cnt) {
      float w = s_w[e];
      uint2 v = ((const uint2*)(xw + (size_t)s_src[e] * O))[tid];
      a0 += w * bf16lo(v.x); a1 += w * bf16hi(v.x);
      a2 += w * bf16lo(v.y); a3 += w * bf16hi(v.y);
    }
  }
  a0 += c0; a1 += c1; a2 += c2; a3 += c3;

  if (PRE) {
    uint2 o; o.x = pack2(a0, a1); o.y = pack2(a2, a3);
    ((uint2*)(h + (size_t)row * O))[tid] = o;
    return;
  }
  float ss = a0 * a0 + a1 * a1 + a2 * a2 + a3 * a3;
#pragma unroll
  for (int off = 32; off > 0; off >>= 1) ss += __shfl_down(ss, off, 64);
  __shared__ float red[(NT + 63) / 64];
  __shared__ float s_scale;
  if ((tid & 63) == 0) red[tid >> 6] = ss;
  __syncthreads();
  if (tid == 0) {
    float t = 0.f;
#pragma unroll
    for (int i = 0; i < (NT + 63) / 64; ++i) t += red[i];
    s_scale = 1.0f / fmaxf(sqrtf(t), 1e-12f);
  }
  __syncthreads();
  float sc = s_scale;
  uint2 o;
  o.x = pack2(fmaxf(a0 * sc, 0.f), fmaxf(a1 * sc, 0.f));
  o.y = pack2(fmaxf(a2 * sc, 0.f), fmaxf(a3 * sc, 0.f));
  ((uint2*)(h + (size_t)row * O))[tid] = o;
}

// ---------------- rowwise l2norm + relu, bf16 in/out, O=1024 ----------------
__global__ __launch_bounds__(256)
void k_l2relu(const u16* __restrict__ t, u16* __restrict__ h) {
  const int row = blockIdx.x;
  const int tid = threadIdx.x;
  const u32* tr = (const u32*)(t + (size_t)row * 1024);
  u32 u0 = tr[tid], u1 = tr[256 + tid];
  float a0 = bf16lo(u0), a1 = bf16hi(u0), a2 = bf16lo(u1), a3 = bf16hi(u1);
  float ss = a0 * a0 + a1 * a1 + a2 * a2 + a3 * a3;
#pragma unroll
  for (int off = 32; off > 0; off >>= 1) ss += __shfl_down(ss, off, 64);
  __shared__ float red[4];
  __shared__ float s_scale;
  if ((tid & 63) == 0) red[tid >> 6] = ss;
  __syncthreads();
  if (tid == 0) {
    float s = red[0] + red[1] + red[2] + red[3];
    s_scale = 1.0f / fmaxf(sqrtf(s), 1e-12f);
  }
  __syncthreads();
  float sc = s_scale;
  u32* hr = (u32*)(h + (size_t)row * 1024);
  hr[tid]       = pack2(fmaxf(a0 * sc, 0.f), fmaxf(a1 * sc, 0.f));
  hr[256 + tid] = pack2(fmaxf(a2 * sc, 0.f), fmaxf(a3 * sc, 0.f));
}

// ---------------- parallel decoder ----------------
__global__ __launch_bounds__(256)
void k_dec_partial(const float* __restrict__ v, const float* __restrict__ W,
                   float* __restrict__ partial, int Kdim, int Ndim) {
  int b = blockIdx.x;
  int lo = b * DCH;
  float rv[DCH];
#pragma unroll
  for (int j = 0; j < DCH; ++j) rv[j] = (lo + j < Kdim) ? v[lo + j] : 0.f;
  for (int n = threadIdx.x; n < Ndim; n += 256) {
    float s = 0.f;
#pragma unroll
    for (int j = 0; j < DCH; ++j)
      if (lo + j < Kdim) s += rv[j] * W[(size_t)(lo + j) * Ndim + n];
    partial[(size_t)b * Ndim + n] = s;
  }
}

template <int ACT>
__global__ __launch_bounds__(256)
void k_dec_combine(const float* __restrict__ partial, const float* __restrict__ bias,
                   float* __restrict__ out, int Ndim) {
  int n = blockIdx.x * 256 + threadIdx.x;
  if (n >= Ndim) return;
  float s = bias[n];
  for (int b = 0; b < DKB; ++b) s += partial[(size_t)b * Ndim + n];
  out[n] = (ACT == 0) ? fmaxf(s, 0.f) : 1.0f / (1.0f + expf(-s));
}

extern "C" void kernel_launch(void* const* d_in, const int* in_sizes, int n_in,
                              void* d_out, int out_size, void* d_ws, size_t ws_size,
                              hipStream_t stream) {
  const float* x    = (const float*)d_in[0];
  const int*   ei   = (const int*)d_in[1];
  const float* ew   = (const float*)d_in[2];
  const float* beta = (const float*)d_in[3];
  const float* yt   = (const float*)d_in[4];
  const float* eps  = (const float*)d_in[5];
  const float* W1   = (const float*)d_in[6];  const float* b1  = (const float*)d_in[7];
  const float* W2   = (const float*)d_in[8];  const float* b2  = (const float*)d_in[9];
  const float* W3   = (const float*)d_in[10]; const float* b3  = (const float*)d_in[11];
  const float* Wmu  = (const float*)d_in[12]; const float* bmu = (const float*)d_in[13];
  const float* Wlv  = (const float*)d_in[14]; const float* blv = (const float*)d_in[15];
  const float* Wd1  = (const float*)d_in[16]; const float* bd1 = (const float*)d_in[17];
  const float* Wd2  = (const float*)d_in[18]; const float* bd2 = (const float*)d_in[19];

  char* wsb = (char*)d_ws;
  size_t off = 0;
  // 16B-aligned workspace allocs (uint2 / dwordx4 natural alignment)
  auto alloc_f = [&](size_t n) { float* p = (float*)(wsb + off); off += ((n * sizeof(float) + 15) & ~(size_t)15); return p; };
  auto alloc_i = [&](size_t n) { int* p = (int*)(wsb + off); off += ((n * sizeof(int) + 15) & ~(size_t)15); return p; };
  auto alloc_h = [&](size_t n) { u16* p = (u16*)(wsb + off); off += ((n * 2 + 15) & ~(size_t)15); return p; };

  int* counts  = alloc_i(NN);
  int* rowptr  = alloc_i(NN + 1);
  int* cursor  = alloc_i(NN);
  int* colsrc  = alloc_i(EE);
  float* ecw   = alloc_f(EE);
  float* dinv  = alloc_f(NN);
  float* din2  = alloc_f(NN);
  float* pmax  = alloc_f((size_t)MTILES * 512);
  float* psum  = alloc_f((size_t)MTILES * 512);
  float* rz    = alloc_f(1028);
  float* hdec  = alloc_f(1028);
  float* part1 = alloc_f((size_t)DKB * 1025);
  float* part2 = alloc_f((size_t)DKB * 1024);
  u16* W1T  = alloc_h(1024 * 512);
  u16* W2T  = alloc_h(512 * 1024);
  u16* W3T  = alloc_h(256 * 512);
  u16* WmuT = alloc_h(512 * 256);
  u16* WlvT = alloc_h(512 * 256);
  u16* xb   = alloc_h((size_t)MPAD * 512);   // x bf16; later reused as h3 (256)
  u16* aggx = alloc_h((size_t)MPAD * 512);   // pre-aggregated x
  u16* bufT = alloc_h((size_t)MPAD * 1024);  // t1; later z2 (512)
  u16* bufH = alloc_h((size_t)MPAD * 1024);  // h1; later z3 (256)
  u16* h2   = alloc_h((size_t)MPAD * 512);
  u16* h3   = xb;
  u16* z2   = bufT;
  u16* z3   = bufH;

  float* out_f  = (float*)d_out;
  float* mu_out = out_f + 1024;
  float* lv_out = out_f + 1024 + (size_t)NN * 512;

  const int MT = MTILES;

  // ---- casts / transposes ----
  k_f2b2<<<4096, 256, 0, stream>>>(x, xb, NN * 512 / 2);
  k_wt_all<<<5632, 256, 0, stream>>>(W1, W2, W3, Wmu, Wlv, W1T, W2T, W3T, WmuT, WlvT);

  // ---- CSR build + degree norms ----
  k_zeroi<<<(NN + 255) / 256, 256, 0, stream>>>(counts, NN);
  k_count<<<(EE + 255) / 256, 256, 0, stream>>>(ei, counts);
  k_scan<<<1, 256, 0, stream>>>(counts, rowptr, cursor);
  k_fill<<<(EE + 255) / 256, 256, 0, stream>>>(ei, ew, cursor, colsrc, ecw);
  k_degcsr<<<(NN + 255) / 256, 256, 0, stream>>>(rowptr, ecw, dinv, din2);

  // ---- layer 1: aggregate x first (linearity), then GEMM+bias, then l2relu ----
  k_gatherv<128, true><<<NN, 128, 0, stream>>>(rowptr, colsrc, ecw, dinv, din2, xb, nullptr, aggx);
  k_mfma<true, true><<<dim3(MT, 8), 256, 0, stream>>>(aggx, W1T, b1, bufT, NN, 512, 1024);
  k_l2relu<<<NN, 256, 0, stream>>>(bufT, bufH);

  // ---- layer 2: GEMM then fused gather+bias+l2relu ----
  k_mfma<true, false><<<dim3(MT, 4), 256, 0, stream>>>(bufH, W2T, nullptr, z2, NN, 1024, 512);
  k_gatherv<128, false><<<NN, 128, 0, stream>>>(rowptr, colsrc, ecw, dinv, din2, z2, b2, h2);

  // ---- layer 3 ----
  k_mfma<true, false><<<dim3(MT, 2), 256, 0, stream>>>(h2, W3T, nullptr, z3, NN, 512, 256);
  k_gatherv<64, false><<<NN, 64, 0, stream>>>(rowptr, colsrc, ecw, dinv, din2, z3, b3, h3);

  // ---- fused VAE heads + reparameterize + partial pooling ----
  k_heads<<<dim3(MT, 4), 256, 0, stream>>>(h3, WmuT, WlvT, bmu, blv, eps, beta,
                                           mu_out, lv_out, pmax, psum);
  k_zred<<<1, 512, 0, stream>>>(pmax, psum, yt, rz);

  // ---- parallel decoder ----
  k_dec_partial<<<DKB, 256, 0, stream>>>(rz, Wd1, part1, 1025, 1025);
  k_dec_combine<0><<<5, 256, 0, stream>>>(part1, bd1, hdec, 1025);
  k_dec_partial<<<DKB, 256, 0, stream>>>(hdec, Wd2, part2, 1025, 1024);
  k_dec_combine<1><<<4, 256, 0, stream>>>(part2, bd2, out_f, 1024);
}

// Round 8
// 665.676 us; speedup vs baseline: 1.0233x; 1.0233x over previous
//
#include <hip/hip_runtime.h>

#define NN 20000
#define EE 320000
#define MPAD 20096   // NN padded to multiple of 128
#define MTILES 157   // ceil(NN/128)
#define DKB 128      // decoder partial blocks
#define DCH 9        // ceil(1025/128)

typedef unsigned short u16;
typedef unsigned int u32;
typedef __attribute__((ext_vector_type(8))) short short8;
typedef __attribute__((ext_vector_type(4))) float f32x4;

// ---------------- bf16 helpers ----------------
__device__ inline float bf16lo(u32 u) { return __uint_as_float(u << 16); }
__device__ inline float bf16hi(u32 u) { return __uint_as_float(u & 0xffff0000u); }
__device__ inline u16 f2b(float f) {
  u32 u = __float_as_uint(f);
  u += 0x7fffu + ((u >> 16) & 1u);
  return (u16)(u >> 16);
}
__device__ inline u32 pack2(float a, float b) {
  return (u32)f2b(a) | ((u32)f2b(b) << 16);
}

__device__ inline void gload16(const void* g, void* l) {
  __builtin_amdgcn_global_load_lds(
      (const __attribute__((address_space(1))) void*)g,
      (__attribute__((address_space(3))) void*)l, 16, 0, 0);
}

// ---------------- zero-init (int) ----------------
__global__ void k_zeroi(int* __restrict__ p, int n) {
  int i = blockIdx.x * blockDim.x + threadIdx.x;
  if (i < n) p[i] = 0;
}

// ---------------- fp32 -> bf16 cast (pairs) ----------------
__global__ void k_f2b2(const float* __restrict__ in, u16* __restrict__ out, int npairs) {
  for (int i = blockIdx.x * blockDim.x + threadIdx.x; i < npairs; i += gridDim.x * blockDim.x) {
    float2 v = *(const float2*)(in + 2 * i);
    ((u32*)out)[i] = pack2(v.x, v.y);
  }
}

// ---------------- all weight transposes in one launch ----------------
// W[K x N] fp32 -> WT[N x K] bf16, 5 matrices by blockIdx range
__global__ void k_wt_all(const float* __restrict__ W1, const float* __restrict__ W2,
                         const float* __restrict__ W3, const float* __restrict__ Wmu,
                         const float* __restrict__ Wlv,
                         u16* __restrict__ T1, u16* __restrict__ T2,
                         u16* __restrict__ T3, u16* __restrict__ Tmu,
                         u16* __restrict__ Tlv) {
  int b = blockIdx.x;
  const float* W; u16* T; int K, N;
  if (b < 2048)      { W = W1;  T = T1;  K = 512;  N = 1024; }
  else if (b < 4096) { W = W2;  T = T2;  K = 1024; N = 512;  b -= 2048; }
  else if (b < 4608) { W = W3;  T = T3;  K = 512;  N = 256;  b -= 4096; }
  else if (b < 5120) { W = Wmu; T = Tmu; K = 256;  N = 512;  b -= 4608; }
  else               { W = Wlv; T = Tlv; K = 256;  N = 512;  b -= 5120; }
  int kb = K >> 8;
  int n = b / kb;
  int k = (b % kb) * 256 + threadIdx.x;
  T[(size_t)n * K + k] = f2b(W[(size_t)k * N + n]);
}

// ---------------- CSR build: count / scan / fill ----------------
__global__ void k_count(const int* __restrict__ ei, int* __restrict__ counts) {
  int e = blockIdx.x * blockDim.x + threadIdx.x;
  if (e < EE) atomicAdd(counts + ei[EE + e], 1);
}

__global__ __launch_bounds__(256)
void k_scan(const int* __restrict__ counts, int* __restrict__ rowptr, int* __restrict__ cursor) {
  const int CHUNK = (NN + 255) / 256;
  int t = threadIdx.x;
  int lo = t * CHUNK, hi = min(lo + CHUNK, NN);
  int s = 0;
  for (int i = lo; i < hi; ++i) s += counts[i];
  __shared__ int tsum[256];
  tsum[t] = s;
  __syncthreads();
  if (t == 0) {
    int run = 0;
    for (int i = 0; i < 256; ++i) { int v = tsum[i]; tsum[i] = run; run += v; }
  }
  __syncthreads();
  int run = tsum[t];
  for (int i = lo; i < hi; ++i) {
    rowptr[i] = run;
    cursor[i] = run;
    run += counts[i];
  }
  if (t == 255) rowptr[NN] = EE;
}

__global__ void k_fill(const int* __restrict__ ei, const float* __restrict__ ew,
                       int* __restrict__ cursor, int* __restrict__ colsrc,
                       float* __restrict__ ecw) {
  int e = blockIdx.x * blockDim.x + threadIdx.x;
  if (e < EE) {
    int d = ei[EE + e];
    int pos = atomicAdd(cursor + d, 1);
    colsrc[pos] = ei[e];
    ecw[pos] = ew[e];
  }
}

__global__ void k_degcsr(const int* __restrict__ rowptr, const float* __restrict__ ecw,
                         float* __restrict__ dinv, float* __restrict__ dinv2) {
  int i = blockIdx.x * blockDim.x + threadIdx.x;
  if (i < NN) {
    float s = 0.f;
    for (int e = rowptr[i]; e < rowptr[i + 1]; ++e) s += ecw[e];
    float d = s + 1.0f;
    dinv[i] = rsqrtf(d);
    dinv2[i] = 1.0f / d;
  }
}

// ---------------- bf16 MFMA GEMM: C[M,N] = A[M,K] @ BT[N,K]^T (+bias) ----------------
template <bool STORE_BF16, bool HAS_BIAS>
__global__ __launch_bounds__(256)
void k_mfma(const u16* __restrict__ A, const u16* __restrict__ BT,
            const float* __restrict__ bias, void* __restrict__ C,
            int M, int K, int N) {
  __shared__ u16 Asm[128 * 32];
  __shared__ u16 Bsm[128 * 32];
  const int tid = threadIdx.x;
  const int m0 = blockIdx.x * 128;
  const int n0 = blockIdx.y * 128;
  const int lane = tid & 63;
  const int wave = tid >> 6;
  const int wm = (wave >> 1) * 64;
  const int wn = (wave & 1) * 64;
  const int qm = lane & 15;
  const int quad = lane >> 4;

  f32x4 acc[4][4];
#pragma unroll
  for (int i = 0; i < 4; ++i)
#pragma unroll
    for (int j = 0; j < 4; ++j) acc[i][j] = (f32x4){0.f, 0.f, 0.f, 0.f};

  for (int k0 = 0; k0 < K; k0 += 32) {
#pragma unroll
    for (int h = 0; h < 2; ++h) {
      int c = h * 256 + tid;
      int row = c >> 2, kc = c & 3;
      gload16(A + (size_t)(m0 + row) * K + k0 + kc * 8, Asm + c * 8);
      gload16(BT + (size_t)(n0 + row) * K + k0 + kc * 8, Bsm + c * 8);
    }
    __syncthreads();
    short8 af[4], bfr[4];
#pragma unroll
    for (int i = 0; i < 4; ++i)
      af[i] = *(const short8*)(Asm + (wm + i * 16 + qm) * 32 + quad * 8);
#pragma unroll
    for (int j = 0; j < 4; ++j)
      bfr[j] = *(const short8*)(Bsm + (wn + j * 16 + qm) * 32 + quad * 8);
#pragma unroll
    for (int i = 0; i < 4; ++i)
#pragma unroll
      for (int j = 0; j < 4; ++j)
        acc[i][j] = __builtin_amdgcn_mfma_f32_16x16x32_bf16(af[i], bfr[j], acc[i][j], 0, 0, 0);
    __syncthreads();
  }

#pragma unroll
  for (int i = 0; i < 4; ++i) {
#pragma unroll
    for (int r = 0; r < 4; ++r) {
      int row = m0 + wm + i * 16 + quad * 4 + r;
      if (row >= M) continue;
#pragma unroll
      for (int j = 0; j < 4; ++j) {
        int col = n0 + wn + j * 16 + qm;
        float v = acc[i][j][r];
        if (HAS_BIAS) v += bias[col];
        if (STORE_BF16) ((u16*)C)[(size_t)row * N + col] = f2b(v);
        else ((float*)C)[(size_t)row * N + col] = v;
      }
    }
  }
}

// ---------------- dual-head MFMA + fused z-pooling ----------------
// v2: 128M x 64N tile (was 128x128) -> acc VGPRs halved (200 -> ~150),
// __launch_bounds__(256,3) pins 3 waves/SIMD; grid doubles to 157x8.
// Theory: kernel is memory-bound (132 MB mandatory traffic) but was at 23%
// HBM with 8% occupancy; more blocks/CU + more waves -> latency hidden.
__global__ __launch_bounds__(256, 3)
void k_heads(const u16* __restrict__ A, const u16* __restrict__ BmuT,
             const u16* __restrict__ BlvT, const float* __restrict__ bmu,
             const float* __restrict__ blv, const float* __restrict__ eps,
             const float* __restrict__ beta_p, float* __restrict__ mu_out,
             float* __restrict__ lv_out, float* __restrict__ pmax,
             float* __restrict__ psum) {
  const int K = 256;
  __shared__ float smemf[4352];  // 17408 B, aliased across phases
  u16* Asm = (u16*)smemf;                    // [0, 8192)      128x32 bf16
  u16* Bmu = (u16*)((char*)smemf + 8192);    // [8192, 12288)  64x32 bf16
  u16* Blv = (u16*)((char*)smemf + 12288);   // [12288, 16384) 64x32 bf16
  float* stmu = smemf;                       // 32*68 floats = 8704 B
  float* stlv = smemf + 32 * 68;             // [8704, 17408)
  const int tid = threadIdx.x;
  const int m0 = blockIdx.x * 128;
  const int n0 = blockIdx.y * 64;            // 64-wide N tile
  const int lane = tid & 63;
  const int wave = tid >> 6;
  const int wm = (wave >> 1) * 64;
  const int wn = (wave & 1) * 32;            // 32-wide per wave
  const int qm = lane & 15;
  const int quad = lane >> 4;

  f32x4 am[4][2], al[4][2];
#pragma unroll
  for (int i = 0; i < 4; ++i)
#pragma unroll
    for (int j = 0; j < 2; ++j) {
      am[i][j] = (f32x4){0.f, 0.f, 0.f, 0.f};
      al[i][j] = (f32x4){0.f, 0.f, 0.f, 0.f};
    }

  for (int k0 = 0; k0 < K; k0 += 32) {
    // A tile: 128x32 = 8192 B -> 2 gload16/thread
#pragma unroll
    for (int h = 0; h < 2; ++h) {
      int c = h * 256 + tid;
      int row = c >> 2, kc = c & 3;
      gload16(A + (size_t)(m0 + row) * K + k0 + kc * 8, Asm + c * 8);
    }
    // B tiles: 64x32 = 4096 B each -> 1 gload16/thread each
    {
      int row = tid >> 2, kc = tid & 3;
      gload16(BmuT + (size_t)(n0 + row) * K + k0 + kc * 8, Bmu + tid * 8);
      gload16(BlvT + (size_t)(n0 + row) * K + k0 + kc * 8, Blv + tid * 8);
    }
    __syncthreads();
    short8 af[4], bm[2], bl[2];
#pragma unroll
    for (int i = 0; i < 4; ++i)
      af[i] = *(const short8*)(Asm + (wm + i * 16 + qm) * 32 + quad * 8);
#pragma unroll
    for (int j = 0; j < 2; ++j) {
      bm[j] = *(const short8*)(Bmu + (wn + j * 16 + qm) * 32 + quad * 8);
      bl[j] = *(const short8*)(Blv + (wn + j * 16 + qm) * 32 + quad * 8);
    }
#pragma unroll
    for (int i = 0; i < 4; ++i)
#pragma unroll
      for (int j = 0; j < 2; ++j) {
        am[i][j] = __builtin_amdgcn_mfma_f32_16x16x32_bf16(af[i], bm[j], am[i][j], 0, 0, 0);
        al[i][j] = __builtin_amdgcn_mfma_f32_16x16x32_bf16(af[i], bl[j], al[i][j], 0, 0, 0);
      }
    __syncthreads();
  }

  const float beta = beta_p[0];
  float biasm[2], biasl[2];
#pragma unroll
  for (int j = 0; j < 2; ++j) {
    int col = n0 + wn + j * 16 + qm;
    biasm[j] = bmu[col];
    biasl[j] = blv[col];
  }

  // per-thread pool partials over 8 fixed columns
  float zmax[8], zsum[8];
#pragma unroll
  for (int q = 0; q < 8; ++q) { zmax[q] = -3.4e38f; zsum[q] = 0.f; }
  const int lrow_r = tid >> 3;        // 0..31
  const int colb = (tid & 7) * 8;     // 0..56

  for (int c = 0; c < 4; ++c) {
    __syncthreads();
    if ((wave >> 1) == (c >> 1)) {
      int ibase = (c & 1) * 2;
#pragma unroll
      for (int ii = 0; ii < 2; ++ii) {
        int i = ibase + ii;
#pragma unroll
        for (int j = 0; j < 2; ++j) {
          int lcol = wn + j * 16 + qm;
#pragma unroll
          for (int r = 0; r < 4; ++r) {
            int lr = ii * 16 + quad * 4 + r;
            stmu[lr * 68 + lcol] = am[i][j][r] + biasm[j];
            stlv[lr * 68 + lcol] = al[i][j][r] + biasl[j];
          }
        }
      }
    }
    __syncthreads();
    int grow = m0 + c * 32 + lrow_r;
    if (grow < NN) {
#pragma unroll
      for (int q4 = 0; q4 < 2; ++q4) {
        int lcol = colb + q4 * 4;
        float4 m4 = *(float4*)(stmu + lrow_r * 68 + lcol);
        float4 l4 = *(float4*)(stlv + lrow_r * 68 + lcol);
        size_t gidx = (size_t)grow * 512 + n0 + lcol;
        float4 e4 = *(const float4*)(eps + gidx);
        *(float4*)(mu_out + gidx) = m4;
        *(float4*)(lv_out + gidx) = l4;
        float z0 = m4.x + 0.01f * e4.x * expf(0.5f * beta * l4.x);
        float z1 = m4.y + 0.01f * e4.y * expf(0.5f * beta * l4.y);
        float z2 = m4.z + 0.01f * e4.z * expf(0.5f * beta * l4.z);
        float z3 = m4.w + 0.01f * e4.w * expf(0.5f * beta * l4.w);
        zmax[q4 * 4 + 0] = fmaxf(zmax[q4 * 4 + 0], z0); zsum[q4 * 4 + 0] += z0;
        zmax[q4 * 4 + 1] = fmaxf(zmax[q4 * 4 + 1], z1); zsum[q4 * 4 + 1] += z1;
        zmax[q4 * 4 + 2] = fmaxf(zmax[q4 * 4 + 2], z2); zsum[q4 * 4 + 2] += z2;
        zmax[q4 * 4 + 3] = fmaxf(zmax[q4 * 4 + 3], z3); zsum[q4 * 4 + 3] += z3;
      }
    }
  }

  // pool reduction: 32 threads (lrow groups) share each 8-col group
  __syncthreads();
  float* rbuf = smemf;  // 256*16 floats = 16384 B
#pragma unroll
  for (int q = 0; q < 8; ++q) {
    rbuf[tid * 16 + q] = zmax[q];
    rbuf[tid * 16 + 8 + q] = zsum[q];
  }
  __syncthreads();
  if (tid < 64) {
    int g = tid >> 3, o = tid & 7;   // col = g*8+o = tid
    float m = -3.4e38f, s = 0.f;
    for (int k = 0; k < 32; ++k) {
      int src = (k * 8 + g) * 16;
      m = fmaxf(m, rbuf[src + o]);
      s += rbuf[src + 8 + o];
    }
    pmax[(size_t)blockIdx.x * 512 + n0 + tid] = m;
    psum[(size_t)blockIdx.x * 512 + n0 + tid] = s;
  }
}

// rz[1025] = [max-pool | mean-pool | y_target], reducing MTILES partials
__global__ void k_zred(const float* __restrict__ pmax, const float* __restrict__ psum,
                       const float* __restrict__ yt, float* __restrict__ rz) {
  int col = threadIdx.x;  // 512 threads
  float m = -3.4e38f, s = 0.f;
  for (int c = 0; c < MTILES; ++c) {
    m = fmaxf(m, pmax[(size_t)c * 512 + col]);
    s += psum[(size_t)c * 512 + col];
  }
  rz[col] = m;
  rz[512 + col] = s / (float)NN;
  if (col == 0) rz[1024] = yt[0];
}

// ---------------- fused CSR gather (bf16 in/out), vectorized: O = 4*NT ----------------
template <int NT, bool PRE>
__global__ __launch_bounds__(NT)
void k_gatherv(const int* __restrict__ rowptr, const int* __restrict__ colsrc,
               const float* __restrict__ ecw, const float* __restrict__ dinv,
               const float* __restrict__ dinv2, const u16* __restrict__ xw,
               const float* __restrict__ bias, u16* __restrict__ h) {
  const int O = 4 * NT;
  const int row = blockIdx.x;
  const int tid = threadIdx.x;
  const float dv = dinv[row], dv2 = dinv2[row];
  uint2 u = ((const uint2*)(xw + (size_t)row * O))[tid];
  float a0 = dv2 * bf16lo(u.x), a1 = dv2 * bf16hi(u.x);
  float a2 = dv2 * bf16lo(u.y), a3 = dv2 * bf16hi(u.y);
  if (!PRE) {
    a0 += bias[4 * tid];     a1 += bias[4 * tid + 1];
    a2 += bias[4 * tid + 2]; a3 += bias[4 * tid + 3];
  }
  float c0 = 0.f, c1 = 0.f, c2 = 0.f, c3 = 0.f;

  __shared__ int s_src[NT];
  __shared__ float s_w[NT];
  const int e0 = rowptr[row], e1 = rowptr[row + 1];
  for (int base = e0; base < e1; base += NT) {
    int cnt = min(NT, e1 - base);
    __syncthreads();
    if (tid < cnt) {
      int s = colsrc[base + tid];
      s_src[tid] = s;
      s_w[tid] = dinv[s] * ecw[base + tid] * dv;
    }
    __syncthreads();
    int e = 0;
    for (; e + 2 <= cnt; e += 2) {
      float w0 = s_w[e], w1 = s_w[e + 1];
      uint2 v0 = ((const uint2*)(xw + (size_t)s_src[e] * O))[tid];
      uint2 v1 = ((const uint2*)(xw + (size_t)s_src[e + 1] * O))[tid];
      a0 += w0 * bf16lo(v0.x); a1 += w0 * bf16hi(v0.x);
      a2 += w0 * bf16lo(v0.y); a3 += w0 * bf16hi(v0.y);
      c0 += w1 * bf16lo(v1.x); c1 += w1 * bf16hi(v1.x);
      c2 += w1 * bf16lo(v1.y); c3 += w1 * bf16hi(v1.y);
    }
    if (e < cnt) {
      float w = s_w[e];
      uint2 v = ((const uint2*)(xw + (size_t)s_src[e] * O))[tid];
      a0 += w * bf16lo(v.x); a1 += w * bf16hi(v.x);
      a2 += w * bf16lo(v.y); a3 += w * bf16hi(v.y);
    }
  }
  a0 += c0; a1 += c1; a2 += c2; a3 += c3;

  if (PRE) {
    uint2 o; o.x = pack2(a0, a1); o.y = pack2(a2, a3);
    ((uint2*)(h + (size_t)row * O))[tid] = o;
    return;
  }
  float ss = a0 * a0 + a1 * a1 + a2 * a2 + a3 * a3;
#pragma unroll
  for (int off = 32; off > 0; off >>= 1) ss += __shfl_down(ss, off, 64);
  __shared__ float red[(NT + 63) / 64];
  __shared__ float s_scale;
  if ((tid & 63) == 0) red[tid >> 6] = ss;
  __syncthreads();
  if (tid == 0) {
    float t = 0.f;
#pragma unroll
    for (int i = 0; i < (NT + 63) / 64; ++i) t += red[i];
    s_scale = 1.0f / fmaxf(sqrtf(t), 1e-12f);
  }
  __syncthreads();
  float sc = s_scale;
  uint2 o;
  o.x = pack2(fmaxf(a0 * sc, 0.f), fmaxf(a1 * sc, 0.f));
  o.y = pack2(fmaxf(a2 * sc, 0.f), fmaxf(a3 * sc, 0.f));
  ((uint2*)(h + (size_t)row * O))[tid] = o;
}

// ---------------- rowwise l2norm + relu, bf16 in/out, O=1024 ----------------
__global__ __launch_bounds__(256)
void k_l2relu(const u16* __restrict__ t, u16* __restrict__ h) {
  const int row = blockIdx.x;
  const int tid = threadIdx.x;
  const u32* tr = (const u32*)(t + (size_t)row * 1024);
  u32 u0 = tr[tid], u1 = tr[256 + tid];
  float a0 = bf16lo(u0), a1 = bf16hi(u0), a2 = bf16lo(u1), a3 = bf16hi(u1);
  float ss = a0 * a0 + a1 * a1 + a2 * a2 + a3 * a3;
#pragma unroll
  for (int off = 32; off > 0; off >>= 1) ss += __shfl_down(ss, off, 64);
  __shared__ float red[4];
  __shared__ float s_scale;
  if ((tid & 63) == 0) red[tid >> 6] = ss;
  __syncthreads();
  if (tid == 0) {
    float s = red[0] + red[1] + red[2] + red[3];
    s_scale = 1.0f / fmaxf(sqrtf(s), 1e-12f);
  }
  __syncthreads();
  float sc = s_scale;
  u32* hr = (u32*)(h + (size_t)row * 1024);
  hr[tid]       = pack2(fmaxf(a0 * sc, 0.f), fmaxf(a1 * sc, 0.f));
  hr[256 + tid] = pack2(fmaxf(a2 * sc, 0.f), fmaxf(a3 * sc, 0.f));
}

// ---------------- parallel decoder ----------------
__global__ __launch_bounds__(256)
void k_dec_partial(const float* __restrict__ v, const float* __restrict__ W,
                   float* __restrict__ partial, int Kdim, int Ndim) {
  int b = blockIdx.x;
  int lo = b * DCH;
  float rv[DCH];
#pragma unroll
  for (int j = 0; j < DCH; ++j) rv[j] = (lo + j < Kdim) ? v[lo + j] : 0.f;
  for (int n = threadIdx.x; n < Ndim; n += 256) {
    float s = 0.f;
#pragma unroll
    for (int j = 0; j < DCH; ++j)
      if (lo + j < Kdim) s += rv[j] * W[(size_t)(lo + j) * Ndim + n];
    partial[(size_t)b * Ndim + n] = s;
  }
}

template <int ACT>
__global__ __launch_bounds__(256)
void k_dec_combine(const float* __restrict__ partial, const float* __restrict__ bias,
                   float* __restrict__ out, int Ndim) {
  int n = blockIdx.x * 256 + threadIdx.x;
  if (n >= Ndim) return;
  float s = bias[n];
  for (int b = 0; b < DKB; ++b) s += partial[(size_t)b * Ndim + n];
  out[n] = (ACT == 0) ? fmaxf(s, 0.f) : 1.0f / (1.0f + expf(-s));
}

extern "C" void kernel_launch(void* const* d_in, const int* in_sizes, int n_in,
                              void* d_out, int out_size, void* d_ws, size_t ws_size,
                              hipStream_t stream) {
  const float* x    = (const float*)d_in[0];
  const int*   ei   = (const int*)d_in[1];
  const float* ew   = (const float*)d_in[2];
  const float* beta = (const float*)d_in[3];
  const float* yt   = (const float*)d_in[4];
  const float* eps  = (const float*)d_in[5];
  const float* W1   = (const float*)d_in[6];  const float* b1  = (const float*)d_in[7];
  const float* W2   = (const float*)d_in[8];  const float* b2  = (const float*)d_in[9];
  const float* W3   = (const float*)d_in[10]; const float* b3  = (const float*)d_in[11];
  const float* Wmu  = (const float*)d_in[12]; const float* bmu = (const float*)d_in[13];
  const float* Wlv  = (const float*)d_in[14]; const float* blv = (const float*)d_in[15];
  const float* Wd1  = (const float*)d_in[16]; const float* bd1 = (const float*)d_in[17];
  const float* Wd2  = (const float*)d_in[18]; const float* bd2 = (const float*)d_in[19];

  char* wsb = (char*)d_ws;
  size_t off = 0;
  // 16B-aligned workspace allocs (uint2 / dwordx4 natural alignment)
  auto alloc_f = [&](size_t n) { float* p = (float*)(wsb + off); off += ((n * sizeof(float) + 15) & ~(size_t)15); return p; };
  auto alloc_i = [&](size_t n) { int* p = (int*)(wsb + off); off += ((n * sizeof(int) + 15) & ~(size_t)15); return p; };
  auto alloc_h = [&](size_t n) { u16* p = (u16*)(wsb + off); off += ((n * 2 + 15) & ~(size_t)15); return p; };

  int* counts  = alloc_i(NN);
  int* rowptr  = alloc_i(NN + 1);
  int* cursor  = alloc_i(NN);
  int* colsrc  = alloc_i(EE);
  float* ecw   = alloc_f(EE);
  float* dinv  = alloc_f(NN);
  float* din2  = alloc_f(NN);
  float* pmax  = alloc_f((size_t)MTILES * 512);
  float* psum  = alloc_f((size_t)MTILES * 512);
  float* rz    = alloc_f(1028);
  float* hdec  = alloc_f(1028);
  float* part1 = alloc_f((size_t)DKB * 1025);
  float* part2 = alloc_f((size_t)DKB * 1024);
  u16* W1T  = alloc_h(1024 * 512);
  u16* W2T  = alloc_h(512 * 1024);
  u16* W3T  = alloc_h(256 * 512);
  u16* WmuT = alloc_h(512 * 256);
  u16* WlvT = alloc_h(512 * 256);
  u16* xb   = alloc_h((size_t)MPAD * 512);   // x bf16; later reused as h3 (256)
  u16* aggx = alloc_h((size_t)MPAD * 512);   // pre-aggregated x
  u16* bufT = alloc_h((size_t)MPAD * 1024);  // t1; later z2 (512)
  u16* bufH = alloc_h((size_t)MPAD * 1024);  // h1; later z3 (256)
  u16* h2   = alloc_h((size_t)MPAD * 512);
  u16* h3   = xb;
  u16* z2   = bufT;
  u16* z3   = bufH;

  float* out_f  = (float*)d_out;
  float* mu_out = out_f + 1024;
  float* lv_out = out_f + 1024 + (size_t)NN * 512;

  const int MT = MTILES;

  // ---- casts / transposes ----
  k_f2b2<<<4096, 256, 0, stream>>>(x, xb, NN * 512 / 2);
  k_wt_all<<<5632, 256, 0, stream>>>(W1, W2, W3, Wmu, Wlv, W1T, W2T, W3T, WmuT, WlvT);

  // ---- CSR build + degree norms ----
  k_zeroi<<<(NN + 255) / 256, 256, 0, stream>>>(counts, NN);
  k_count<<<(EE + 255) / 256, 256, 0, stream>>>(ei, counts);
  k_scan<<<1, 256, 0, stream>>>(counts, rowptr, cursor);
  k_fill<<<(EE + 255) / 256, 256, 0, stream>>>(ei, ew, cursor, colsrc, ecw);
  k_degcsr<<<(NN + 255) / 256, 256, 0, stream>>>(rowptr, ecw, dinv, din2);

  // ---- layer 1: aggregate x first (linearity), then GEMM+bias, then l2relu ----
  k_gatherv<128, true><<<NN, 128, 0, stream>>>(rowptr, colsrc, ecw, dinv, din2, xb, nullptr, aggx);
  k_mfma<true, true><<<dim3(MT, 8), 256, 0, stream>>>(aggx, W1T, b1, bufT, NN, 512, 1024);
  k_l2relu<<<NN, 256, 0, stream>>>(bufT, bufH);

  // ---- layer 2: GEMM then fused gather+bias+l2relu ----
  k_mfma<true, false><<<dim3(MT, 4), 256, 0, stream>>>(bufH, W2T, nullptr, z2, NN, 1024, 512);
  k_gatherv<128, false><<<NN, 128, 0, stream>>>(rowptr, colsrc, ecw, dinv, din2, z2, b2, h2);

  // ---- layer 3 ----
  k_mfma<true, false><<<dim3(MT, 2), 256, 0, stream>>>(h2, W3T, nullptr, z3, NN, 512, 256);
  k_gatherv<64, false><<<NN, 64, 0, stream>>>(rowptr, colsrc, ecw, dinv, din2, z3, b3, h3);

  // ---- fused VAE heads + reparameterize + partial pooling (64-wide N tiles) ----
  k_heads<<<dim3(MT, 8), 256, 0, stream>>>(h3, WmuT, WlvT, bmu, blv, eps, beta,
                                           mu_out, lv_out, pmax, psum);
  k_zred<<<1, 512, 0, stream>>>(pmax, psum, yt, rz);

  // ---- parallel decoder ----
  k_dec_partial<<<DKB, 256, 0, stream>>>(rz, Wd1, part1, 1025, 1025);
  k_dec_combine<0><<<5, 256, 0, stream>>>(part1, bd1, hdec, 1025);
  k_dec_partial<<<DKB, 256, 0, stream>>>(hdec, Wd2, part2, 1025, 1024);
  k_dec_combine<1><<<4, 256, 0, stream>>>(part2, bd2, out_f, 1024);
}

// Round 9
// 645.243 us; speedup vs baseline: 1.0557x; 1.0317x over previous
//
#include <hip/hip_runtime.h>

#define NN 20000
#define EE 320000
#define MPAD 20096   // NN padded to multiple of 128
#define MTILES 157   // ceil(NN/128)
#define DKB 128      // decoder partial blocks
#define DCH 9        // ceil(1025/128)

typedef unsigned short u16;
typedef unsigned int u32;
typedef __attribute__((ext_vector_type(8))) short short8;
typedef __attribute__((ext_vector_type(4))) float f32x4;

// ---------------- bf16 helpers ----------------
__device__ inline float bf16lo(u32 u) { return __uint_as_float(u << 16); }
__device__ inline float bf16hi(u32 u) { return __uint_as_float(u & 0xffff0000u); }
__device__ inline u16 f2b(float f) {
  u32 u = __float_as_uint(f);
  u += 0x7fffu + ((u >> 16) & 1u);
  return (u16)(u >> 16);
}
__device__ inline u32 pack2(float a, float b) {
  return (u32)f2b(a) | ((u32)f2b(b) << 16);
}

__device__ inline void gload16(const void* g, void* l) {
  __builtin_amdgcn_global_load_lds(
      (const __attribute__((address_space(1))) void*)g,
      (__attribute__((address_space(3))) void*)l, 16, 0, 0);
}

// XCD-chunked bijective block map (m204 formula): hardware assigns
// xcd = wg % 8; give each XCD a CONTIGUOUS range of ord = mt*ntn + nt
// (m-major) so its L2 holds one A-chunk + all of B instead of thrashing.
__device__ inline int xcd_ord(int wg, int nwg) {
  int q = nwg >> 3, r = nwg & 7;
  int xcd = wg & 7, k = wg >> 3;
  return xcd * q + min(xcd, r) + k;
}

// ---------------- zero-init (int) ----------------
__global__ void k_zeroi(int* __restrict__ p, int n) {
  int i = blockIdx.x * blockDim.x + threadIdx.x;
  if (i < n) p[i] = 0;
}

// ---------------- fp32 -> bf16 cast (pairs) ----------------
__global__ void k_f2b2(const float* __restrict__ in, u16* __restrict__ out, int npairs) {
  for (int i = blockIdx.x * blockDim.x + threadIdx.x; i < npairs; i += gridDim.x * blockDim.x) {
    float2 v = *(const float2*)(in + 2 * i);
    ((u32*)out)[i] = pack2(v.x, v.y);
  }
}

// ---------------- all weight transposes in one launch ----------------
// W[K x N] fp32 -> WT[N x K] bf16, 5 matrices by blockIdx range
__global__ void k_wt_all(const float* __restrict__ W1, const float* __restrict__ W2,
                         const float* __restrict__ W3, const float* __restrict__ Wmu,
                         const float* __restrict__ Wlv,
                         u16* __restrict__ T1, u16* __restrict__ T2,
                         u16* __restrict__ T3, u16* __restrict__ Tmu,
                         u16* __restrict__ Tlv) {
  int b = blockIdx.x;
  const float* W; u16* T; int K, N;
  if (b < 2048)      { W = W1;  T = T1;  K = 512;  N = 1024; }
  else if (b < 4096) { W = W2;  T = T2;  K = 1024; N = 512;  b -= 2048; }
  else if (b < 4608) { W = W3;  T = T3;  K = 512;  N = 256;  b -= 4096; }
  else if (b < 5120) { W = Wmu; T = Tmu; K = 256;  N = 512;  b -= 4608; }
  else               { W = Wlv; T = Tlv; K = 256;  N = 512;  b -= 5120; }
  int kb = K >> 8;
  int n = b / kb;
  int k = (b % kb) * 256 + threadIdx.x;
  T[(size_t)n * K + k] = f2b(W[(size_t)k * N + n]);
}

// ---------------- CSR build: count / scan / fill ----------------
__global__ void k_count(const int* __restrict__ ei, int* __restrict__ counts) {
  int e = blockIdx.x * blockDim.x + threadIdx.x;
  if (e < EE) atomicAdd(counts + ei[EE + e], 1);
}

__global__ __launch_bounds__(256)
void k_scan(const int* __restrict__ counts, int* __restrict__ rowptr, int* __restrict__ cursor) {
  const int CHUNK = (NN + 255) / 256;
  int t = threadIdx.x;
  int lo = t * CHUNK, hi = min(lo + CHUNK, NN);
  int s = 0;
  for (int i = lo; i < hi; ++i) s += counts[i];
  __shared__ int tsum[256];
  tsum[t] = s;
  __syncthreads();
  if (t == 0) {
    int run = 0;
    for (int i = 0; i < 256; ++i) { int v = tsum[i]; tsum[i] = run; run += v; }
  }
  __syncthreads();
  int run = tsum[t];
  for (int i = lo; i < hi; ++i) {
    rowptr[i] = run;
    cursor[i] = run;
    run += counts[i];
  }
  if (t == 255) rowptr[NN] = EE;
}

__global__ void k_fill(const int* __restrict__ ei, const float* __restrict__ ew,
                       int* __restrict__ cursor, int* __restrict__ colsrc,
                       float* __restrict__ ecw) {
  int e = blockIdx.x * blockDim.x + threadIdx.x;
  if (e < EE) {
    int d = ei[EE + e];
    int pos = atomicAdd(cursor + d, 1);
    colsrc[pos] = ei[e];
    ecw[pos] = ew[e];
  }
}

__global__ void k_degcsr(const int* __restrict__ rowptr, const float* __restrict__ ecw,
                         float* __restrict__ dinv, float* __restrict__ dinv2) {
  int i = blockIdx.x * blockDim.x + threadIdx.x;
  if (i < NN) {
    float s = 0.f;
    for (int e = rowptr[i]; e < rowptr[i + 1]; ++e) s += ecw[e];
    float d = s + 1.0f;
    dinv[i] = rsqrtf(d);
    dinv2[i] = 1.0f / d;
  }
}

// ---------------- bf16 MFMA GEMM: C[M,N] = A[M,K] @ BT[N,K]^T (+bias) ----------------
// 1D grid, XCD-chunked m-major mapping: per-XCD working set = contiguous
// A-chunk (~A/8) + all of B -> fits 4MB L2 (was: every-8th-panel thrash,
// FETCH 96MB vs 22MB compulsory at L1 shape).
template <bool STORE_BF16, bool HAS_BIAS>
__global__ __launch_bounds__(256)
void k_mfma(const u16* __restrict__ A, const u16* __restrict__ BT,
            const float* __restrict__ bias, void* __restrict__ C,
            int M, int K, int N) {
  __shared__ u16 Asm[128 * 32];
  __shared__ u16 Bsm[128 * 32];
  const int tid = threadIdx.x;
  const int ntn = N >> 7;
  int ord = xcd_ord(blockIdx.x, gridDim.x);
  const int m0 = (ord / ntn) * 128;
  const int n0 = (ord % ntn) * 128;
  const int lane = tid & 63;
  const int wave = tid >> 6;
  const int wm = (wave >> 1) * 64;
  const int wn = (wave & 1) * 64;
  const int qm = lane & 15;
  const int quad = lane >> 4;

  f32x4 acc[4][4];
#pragma unroll
  for (int i = 0; i < 4; ++i)
#pragma unroll
    for (int j = 0; j < 4; ++j) acc[i][j] = (f32x4){0.f, 0.f, 0.f, 0.f};

  for (int k0 = 0; k0 < K; k0 += 32) {
#pragma unroll
    for (int h = 0; h < 2; ++h) {
      int c = h * 256 + tid;
      int row = c >> 2, kc = c & 3;
      gload16(A + (size_t)(m0 + row) * K + k0 + kc * 8, Asm + c * 8);
      gload16(BT + (size_t)(n0 + row) * K + k0 + kc * 8, Bsm + c * 8);
    }
    __syncthreads();
    short8 af[4], bfr[4];
#pragma unroll
    for (int i = 0; i < 4; ++i)
      af[i] = *(const short8*)(Asm + (wm + i * 16 + qm) * 32 + quad * 8);
#pragma unroll
    for (int j = 0; j < 4; ++j)
      bfr[j] = *(const short8*)(Bsm + (wn + j * 16 + qm) * 32 + quad * 8);
#pragma unroll
    for (int i = 0; i < 4; ++i)
#pragma unroll
      for (int j = 0; j < 4; ++j)
        acc[i][j] = __builtin_amdgcn_mfma_f32_16x16x32_bf16(af[i], bfr[j], acc[i][j], 0, 0, 0);
    __syncthreads();
  }

#pragma unroll
  for (int i = 0; i < 4; ++i) {
#pragma unroll
    for (int r = 0; r < 4; ++r) {
      int row = m0 + wm + i * 16 + quad * 4 + r;
      if (row >= M) continue;
#pragma unroll
      for (int j = 0; j < 4; ++j) {
        int col = n0 + wn + j * 16 + qm;
        float v = acc[i][j][r];
        if (HAS_BIAS) v += bias[col];
        if (STORE_BF16) ((u16*)C)[(size_t)row * N + col] = f2b(v);
        else ((float*)C)[(size_t)row * N + col] = v;
      }
    }
  }
}

// ---------------- dual-head MFMA + fused z-pooling ----------------
// v2: 128M x 64N tile, __launch_bounds__(256,3); v3: + XCD-chunked map.
__global__ __launch_bounds__(256, 3)
void k_heads(const u16* __restrict__ A, const u16* __restrict__ BmuT,
             const u16* __restrict__ BlvT, const float* __restrict__ bmu,
             const float* __restrict__ blv, const float* __restrict__ eps,
             const float* __restrict__ beta_p, float* __restrict__ mu_out,
             float* __restrict__ lv_out, float* __restrict__ pmax,
             float* __restrict__ psum) {
  const int K = 256;
  __shared__ float smemf[4352];  // 17408 B, aliased across phases
  u16* Asm = (u16*)smemf;                    // [0, 8192)      128x32 bf16
  u16* Bmu = (u16*)((char*)smemf + 8192);    // [8192, 12288)  64x32 bf16
  u16* Blv = (u16*)((char*)smemf + 12288);   // [12288, 16384) 64x32 bf16
  float* stmu = smemf;                       // 32*68 floats = 8704 B
  float* stlv = smemf + 32 * 68;             // [8704, 17408)
  const int tid = threadIdx.x;
  int ord = xcd_ord(blockIdx.x, gridDim.x);
  const int mt = ord >> 3;                   // ntn = 8
  const int m0 = mt * 128;
  const int n0 = (ord & 7) * 64;             // 64-wide N tile
  const int lane = tid & 63;
  const int wave = tid >> 6;
  const int wm = (wave >> 1) * 64;
  const int wn = (wave & 1) * 32;            // 32-wide per wave
  const int qm = lane & 15;
  const int quad = lane >> 4;

  f32x4 am[4][2], al[4][2];
#pragma unroll
  for (int i = 0; i < 4; ++i)
#pragma unroll
    for (int j = 0; j < 2; ++j) {
      am[i][j] = (f32x4){0.f, 0.f, 0.f, 0.f};
      al[i][j] = (f32x4){0.f, 0.f, 0.f, 0.f};
    }

  for (int k0 = 0; k0 < K; k0 += 32) {
    // A tile: 128x32 = 8192 B -> 2 gload16/thread
#pragma unroll
    for (int h = 0; h < 2; ++h) {
      int c = h * 256 + tid;
      int row = c >> 2, kc = c & 3;
      gload16(A + (size_t)(m0 + row) * K + k0 + kc * 8, Asm + c * 8);
    }
    // B tiles: 64x32 = 4096 B each -> 1 gload16/thread each
    {
      int row = tid >> 2, kc = tid & 3;
      gload16(BmuT + (size_t)(n0 + row) * K + k0 + kc * 8, Bmu + tid * 8);
      gload16(BlvT + (size_t)(n0 + row) * K + k0 + kc * 8, Blv + tid * 8);
    }
    __syncthreads();
    short8 af[4], bm[2], bl[2];
#pragma unroll
    for (int i = 0; i < 4; ++i)
      af[i] = *(const short8*)(Asm + (wm + i * 16 + qm) * 32 + quad * 8);
#pragma unroll
    for (int j = 0; j < 2; ++j) {
      bm[j] = *(const short8*)(Bmu + (wn + j * 16 + qm) * 32 + quad * 8);
      bl[j] = *(const short8*)(Blv + (wn + j * 16 + qm) * 32 + quad * 8);
    }
#pragma unroll
    for (int i = 0; i < 4; ++i)
#pragma unroll
      for (int j = 0; j < 2; ++j) {
        am[i][j] = __builtin_amdgcn_mfma_f32_16x16x32_bf16(af[i], bm[j], am[i][j], 0, 0, 0);
        al[i][j] = __builtin_amdgcn_mfma_f32_16x16x32_bf16(af[i], bl[j], al[i][j], 0, 0, 0);
      }
    __syncthreads();
  }

  const float beta = beta_p[0];
  float biasm[2], biasl[2];
#pragma unroll
  for (int j = 0; j < 2; ++j) {
    int col = n0 + wn + j * 16 + qm;
    biasm[j] = bmu[col];
    biasl[j] = blv[col];
  }

  // per-thread pool partials over 8 fixed columns
  float zmax[8], zsum[8];
#pragma unroll
  for (int q = 0; q < 8; ++q) { zmax[q] = -3.4e38f; zsum[q] = 0.f; }
  const int lrow_r = tid >> 3;        // 0..31
  const int colb = (tid & 7) * 8;     // 0..56

  for (int c = 0; c < 4; ++c) {
    __syncthreads();
    if ((wave >> 1) == (c >> 1)) {
      int ibase = (c & 1) * 2;
#pragma unroll
      for (int ii = 0; ii < 2; ++ii) {
        int i = ibase + ii;
#pragma unroll
        for (int j = 0; j < 2; ++j) {
          int lcol = wn + j * 16 + qm;
#pragma unroll
          for (int r = 0; r < 4; ++r) {
            int lr = ii * 16 + quad * 4 + r;
            stmu[lr * 68 + lcol] = am[i][j][r] + biasm[j];
            stlv[lr * 68 + lcol] = al[i][j][r] + biasl[j];
          }
        }
      }
    }
    __syncthreads();
    int grow = m0 + c * 32 + lrow_r;
    if (grow < NN) {
#pragma unroll
      for (int q4 = 0; q4 < 2; ++q4) {
        int lcol = colb + q4 * 4;
        float4 m4 = *(float4*)(stmu + lrow_r * 68 + lcol);
        float4 l4 = *(float4*)(stlv + lrow_r * 68 + lcol);
        size_t gidx = (size_t)grow * 512 + n0 + lcol;
        float4 e4 = *(const float4*)(eps + gidx);
        *(float4*)(mu_out + gidx) = m4;
        *(float4*)(lv_out + gidx) = l4;
        float z0 = m4.x + 0.01f * e4.x * expf(0.5f * beta * l4.x);
        float z1 = m4.y + 0.01f * e4.y * expf(0.5f * beta * l4.y);
        float z2 = m4.z + 0.01f * e4.z * expf(0.5f * beta * l4.z);
        float z3 = m4.w + 0.01f * e4.w * expf(0.5f * beta * l4.w);
        zmax[q4 * 4 + 0] = fmaxf(zmax[q4 * 4 + 0], z0); zsum[q4 * 4 + 0] += z0;
        zmax[q4 * 4 + 1] = fmaxf(zmax[q4 * 4 + 1], z1); zsum[q4 * 4 + 1] += z1;
        zmax[q4 * 4 + 2] = fmaxf(zmax[q4 * 4 + 2], z2); zsum[q4 * 4 + 2] += z2;
        zmax[q4 * 4 + 3] = fmaxf(zmax[q4 * 4 + 3], z3); zsum[q4 * 4 + 3] += z3;
      }
    }
  }

  // pool reduction: 32 threads (lrow groups) share each 8-col group
  __syncthreads();
  float* rbuf = smemf;  // 256*16 floats = 16384 B
#pragma unroll
  for (int q = 0; q < 8; ++q) {
    rbuf[tid * 16 + q] = zmax[q];
    rbuf[tid * 16 + 8 + q] = zsum[q];
  }
  __syncthreads();
  if (tid < 64) {
    int g = tid >> 3, o = tid & 7;   // col = g*8+o = tid
    float m = -3.4e38f, s = 0.f;
    for (int k = 0; k < 32; ++k) {
      int src = (k * 8 + g) * 16;
      m = fmaxf(m, rbuf[src + o]);
      s += rbuf[src + 8 + o];
    }
    pmax[(size_t)mt * 512 + n0 + tid] = m;
    psum[(size_t)mt * 512 + n0 + tid] = s;
  }
}

// rz[1025] = [max-pool | mean-pool | y_target], reducing MTILES partials
__global__ void k_zred(const float* __restrict__ pmax, const float* __restrict__ psum,
                       const float* __restrict__ yt, float* __restrict__ rz) {
  int col = threadIdx.x;  // 512 threads
  float m = -3.4e38f, s = 0.f;
  for (int c = 0; c < MTILES; ++c) {
    m = fmaxf(m, pmax[(size_t)c * 512 + col]);
    s += psum[(size_t)c * 512 + col];
  }
  rz[col] = m;
  rz[512 + col] = s / (float)NN;
  if (col == 0) rz[1024] = yt[0];
}

// ---------------- fused CSR gather (bf16 in/out), vectorized: O = 4*NT ----------------
template <int NT, bool PRE>
__global__ __launch_bounds__(NT)
void k_gatherv(const int* __restrict__ rowptr, const int* __restrict__ colsrc,
               const float* __restrict__ ecw, const float* __restrict__ dinv,
               const float* __restrict__ dinv2, const u16* __restrict__ xw,
               const float* __restrict__ bias, u16* __restrict__ h) {
  const int O = 4 * NT;
  const int row = blockIdx.x;
  const int tid = threadIdx.x;
  const float dv = dinv[row], dv2 = dinv2[row];
  uint2 u = ((const uint2*)(xw + (size_t)row * O))[tid];
  float a0 = dv2 * bf16lo(u.x), a1 = dv2 * bf16hi(u.x);
  float a2 = dv2 * bf16lo(u.y), a3 = dv2 * bf16hi(u.y);
  if (!PRE) {
    a0 += bias[4 * tid];     a1 += bias[4 * tid + 1];
    a2 += bias[4 * tid + 2]; a3 += bias[4 * tid + 3];
  }
  float c0 = 0.f, c1 = 0.f, c2 = 0.f, c3 = 0.f;

  __shared__ int s_src[NT];
  __shared__ float s_w[NT];
  const int e0 = rowptr[row], e1 = rowptr[row + 1];
  for (int base = e0; base < e1; base += NT) {
    int cnt = min(NT, e1 - base);
    __syncthreads();
    if (tid < cnt) {
      int s = colsrc[base + tid];
      s_src[tid] = s;
      s_w[tid] = dinv[s] * ecw[base + tid] * dv;
    }
    __syncthreads();
    int e = 0;
    for (; e + 2 <= cnt; e += 2) {
      float w0 = s_w[e], w1 = s_w[e + 1];
      uint2 v0 = ((const uint2*)(xw + (size_t)s_src[e] * O))[tid];
      uint2 v1 = ((const uint2*)(xw + (size_t)s_src[e + 1] * O))[tid];
      a0 += w0 * bf16lo(v0.x); a1 += w0 * bf16hi(v0.x);
      a2 += w0 * bf16lo(v0.y); a3 += w0 * bf16hi(v0.y);
      c0 += w1 * bf16lo(v1.x); c1 += w1 * bf16hi(v1.x);
      c2 += w1 * bf16lo(v1.y); c3 += w1 * bf16hi(v1.y);
    }
    if (e < cnt) {
      float w = s_w[e];
      uint2 v = ((const uint2*)(xw + (size_t)s_src[e] * O))[tid];
      a0 += w * bf16lo(v.x); a1 += w * bf16hi(v.x);
      a2 += w * bf16lo(v.y); a3 += w * bf16hi(v.y);
    }
  }
  a0 += c0; a1 += c1; a2 += c2; a3 += c3;

  if (PRE) {
    uint2 o; o.x = pack2(a0, a1); o.y = pack2(a2, a3);
    ((uint2*)(h + (size_t)row * O))[tid] = o;
    return;
  }
  float ss = a0 * a0 + a1 * a1 + a2 * a2 + a3 * a3;
#pragma unroll
  for (int off = 32; off > 0; off >>= 1) ss += __shfl_down(ss, off, 64);
  __shared__ float red[(NT + 63) / 64];
  __shared__ float s_scale;
  if ((tid & 63) == 0) red[tid >> 6] = ss;
  __syncthreads();
  if (tid == 0) {
    float t = 0.f;
#pragma unroll
    for (int i = 0; i < (NT + 63) / 64; ++i) t += red[i];
    s_scale = 1.0f / fmaxf(sqrtf(t), 1e-12f);
  }
  __syncthreads();
  float sc = s_scale;
  uint2 o;
  o.x = pack2(fmaxf(a0 * sc, 0.f), fmaxf(a1 * sc, 0.f));
  o.y = pack2(fmaxf(a2 * sc, 0.f), fmaxf(a3 * sc, 0.f));
  ((uint2*)(h + (size_t)row * O))[tid] = o;
}

// ---------------- rowwise l2norm + relu, bf16 in/out, O=1024 ----------------
__global__ __launch_bounds__(256)
void k_l2relu(const u16* __restrict__ t, u16* __restrict__ h) {
  const int row = blockIdx.x;
  const int tid = threadIdx.x;
  const u32* tr = (const u32*)(t + (size_t)row * 1024);
  u32 u0 = tr[tid], u1 = tr[256 + tid];
  float a0 = bf16lo(u0), a1 = bf16hi(u0), a2 = bf16lo(u1), a3 = bf16hi(u1);
  float ss = a0 * a0 + a1 * a1 + a2 * a2 + a3 * a3;
#pragma unroll
  for (int off = 32; off > 0; off >>= 1) ss += __shfl_down(ss, off, 64);
  __shared__ float red[4];
  __shared__ float s_scale;
  if ((tid & 63) == 0) red[tid >> 6] = ss;
  __syncthreads();
  if (tid == 0) {
    float s = red[0] + red[1] + red[2] + red[3];
    s_scale = 1.0f / fmaxf(sqrtf(s), 1e-12f);
  }
  __syncthreads();
  float sc = s_scale;
  u32* hr = (u32*)(h + (size_t)row * 1024);
  hr[tid]       = pack2(fmaxf(a0 * sc, 0.f), fmaxf(a1 * sc, 0.f));
  hr[256 + tid] = pack2(fmaxf(a2 * sc, 0.f), fmaxf(a3 * sc, 0.f));
}

// ---------------- parallel decoder ----------------
__global__ __launch_bounds__(256)
void k_dec_partial(const float* __restrict__ v, const float* __restrict__ W,
                   float* __restrict__ partial, int Kdim, int Ndim) {
  int b = blockIdx.x;
  int lo = b * DCH;
  float rv[DCH];
#pragma unroll
  for (int j = 0; j < DCH; ++j) rv[j] = (lo + j < Kdim) ? v[lo + j] : 0.f;
  for (int n = threadIdx.x; n < Ndim; n += 256) {
    float s = 0.f;
#pragma unroll
    for (int j = 0; j < DCH; ++j)
      if (lo + j < Kdim) s += rv[j] * W[(size_t)(lo + j) * Ndim + n];
    partial[(size_t)b * Ndim + n] = s;
  }
}

template <int ACT>
__global__ __launch_bounds__(256)
void k_dec_combine(const float* __restrict__ partial, const float* __restrict__ bias,
                   float* __restrict__ out, int Ndim) {
  int n = blockIdx.x * 256 + threadIdx.x;
  if (n >= Ndim) return;
  float s = bias[n];
  for (int b = 0; b < DKB; ++b) s += partial[(size_t)b * Ndim + n];
  out[n] = (ACT == 0) ? fmaxf(s, 0.f) : 1.0f / (1.0f + expf(-s));
}

extern "C" void kernel_launch(void* const* d_in, const int* in_sizes, int n_in,
                              void* d_out, int out_size, void* d_ws, size_t ws_size,
                              hipStream_t stream) {
  const float* x    = (const float*)d_in[0];
  const int*   ei   = (const int*)d_in[1];
  const float* ew   = (const float*)d_in[2];
  const float* beta = (const float*)d_in[3];
  const float* yt   = (const float*)d_in[4];
  const float* eps  = (const float*)d_in[5];
  const float* W1   = (const float*)d_in[6];  const float* b1  = (const float*)d_in[7];
  const float* W2   = (const float*)d_in[8];  const float* b2  = (const float*)d_in[9];
  const float* W3   = (const float*)d_in[10]; const float* b3  = (const float*)d_in[11];
  const float* Wmu  = (const float*)d_in[12]; const float* bmu = (const float*)d_in[13];
  const float* Wlv  = (const float*)d_in[14]; const float* blv = (const float*)d_in[15];
  const float* Wd1  = (const float*)d_in[16]; const float* bd1 = (const float*)d_in[17];
  const float* Wd2  = (const float*)d_in[18]; const float* bd2 = (const float*)d_in[19];

  char* wsb = (char*)d_ws;
  size_t off = 0;
  // 16B-aligned workspace allocs (uint2 / dwordx4 natural alignment)
  auto alloc_f = [&](size_t n) { float* p = (float*)(wsb + off); off += ((n * sizeof(float) + 15) & ~(size_t)15); return p; };
  auto alloc_i = [&](size_t n) { int* p = (int*)(wsb + off); off += ((n * sizeof(int) + 15) & ~(size_t)15); return p; };
  auto alloc_h = [&](size_t n) { u16* p = (u16*)(wsb + off); off += ((n * 2 + 15) & ~(size_t)15); return p; };

  int* counts  = alloc_i(NN);
  int* rowptr  = alloc_i(NN + 1);
  int* cursor  = alloc_i(NN);
  int* colsrc  = alloc_i(EE);
  float* ecw   = alloc_f(EE);
  float* dinv  = alloc_f(NN);
  float* din2  = alloc_f(NN);
  float* pmax  = alloc_f((size_t)MTILES * 512);
  float* psum  = alloc_f((size_t)MTILES * 512);
  float* rz    = alloc_f(1028);
  float* hdec  = alloc_f(1028);
  float* part1 = alloc_f((size_t)DKB * 1025);
  float* part2 = alloc_f((size_t)DKB * 1024);
  u16* W1T  = alloc_h(1024 * 512);
  u16* W2T  = alloc_h(512 * 1024);
  u16* W3T  = alloc_h(256 * 512);
  u16* WmuT = alloc_h(512 * 256);
  u16* WlvT = alloc_h(512 * 256);
  u16* xb   = alloc_h((size_t)MPAD * 512);   // x bf16; later reused as h3 (256)
  u16* aggx = alloc_h((size_t)MPAD * 512);   // pre-aggregated x
  u16* bufT = alloc_h((size_t)MPAD * 1024);  // t1; later z2 (512)
  u16* bufH = alloc_h((size_t)MPAD * 1024);  // h1; later z3 (256)
  u16* h2   = alloc_h((size_t)MPAD * 512);
  u16* h3   = xb;
  u16* z2   = bufT;
  u16* z3   = bufH;

  float* out_f  = (float*)d_out;
  float* mu_out = out_f + 1024;
  float* lv_out = out_f + 1024 + (size_t)NN * 512;

  const int MT = MTILES;

  // ---- casts / transposes ----
  k_f2b2<<<4096, 256, 0, stream>>>(x, xb, NN * 512 / 2);
  k_wt_all<<<5632, 256, 0, stream>>>(W1, W2, W3, Wmu, Wlv, W1T, W2T, W3T, WmuT, WlvT);

  // ---- CSR build + degree norms ----
  k_zeroi<<<(NN + 255) / 256, 256, 0, stream>>>(counts, NN);
  k_count<<<(EE + 255) / 256, 256, 0, stream>>>(ei, counts);
  k_scan<<<1, 256, 0, stream>>>(counts, rowptr, cursor);
  k_fill<<<(EE + 255) / 256, 256, 0, stream>>>(ei, ew, cursor, colsrc, ecw);
  k_degcsr<<<(NN + 255) / 256, 256, 0, stream>>>(rowptr, ecw, dinv, din2);

  // ---- layer 1: aggregate x first (linearity), then GEMM+bias, then l2relu ----
  k_gatherv<128, true><<<NN, 128, 0, stream>>>(rowptr, colsrc, ecw, dinv, din2, xb, nullptr, aggx);
  k_mfma<true, true><<<MT * 8, 256, 0, stream>>>(aggx, W1T, b1, bufT, NN, 512, 1024);
  k_l2relu<<<NN, 256, 0, stream>>>(bufT, bufH);

  // ---- layer 2: GEMM then fused gather+bias+l2relu ----
  k_mfma<true, false><<<MT * 4, 256, 0, stream>>>(bufH, W2T, nullptr, z2, NN, 1024, 512);
  k_gatherv<128, false><<<NN, 128, 0, stream>>>(rowptr, colsrc, ecw, dinv, din2, z2, b2, h2);

  // ---- layer 3 ----
  k_mfma<true, false><<<MT * 2, 256, 0, stream>>>(h2, W3T, nullptr, z3, NN, 512, 256);
  k_gatherv<64, false><<<NN, 64, 0, stream>>>(rowptr, colsrc, ecw, dinv, din2, z3, b3, h3);

  // ---- fused VAE heads + reparameterize + partial pooling (64-wide N tiles) ----
  k_heads<<<MT * 8, 256, 0, stream>>>(h3, WmuT, WlvT, bmu, blv, eps, beta,
                                      mu_out, lv_out, pmax, psum);
  k_zred<<<1, 512, 0, stream>>>(pmax, psum, yt, rz);

  // ---- parallel decoder ----
  k_dec_partial<<<DKB, 256, 0, stream>>>(rz, Wd1, part1, 1025, 1025);
  k_dec_combine<0><<<5, 256, 0, stream>>>(part1, bd1, hdec, 1025);
  k_dec_partial<<<DKB, 256, 0, stream>>>(hdec, Wd2, part2, 1025, 1024);
  k_dec_combine<1><<<4, 256, 0, stream>>>(part2, bd2, out_f, 1024);
}

// Round 10
// 641.137 us; speedup vs baseline: 1.0625x; 1.0064x over previous
//
#include <hip/hip_runtime.h>

#define NN 20000
#define EE 320000
#define MPAD 20096   // NN padded to multiple of 128
#define MTILES 157   // ceil(NN/128)
#define DKB 128      // decoder partial blocks
#define DCH 9        // ceil(1025/128)

typedef unsigned short u16;
typedef unsigned int u32;
typedef __attribute__((ext_vector_type(8))) short short8;
typedef __attribute__((ext_vector_type(4))) float f32x4;

// ---------------- bf16 helpers ----------------
__device__ inline float bf16lo(u32 u) { return __uint_as_float(u << 16); }
__device__ inline float bf16hi(u32 u) { return __uint_as_float(u & 0xffff0000u); }
__device__ inline u16 f2b(float f) {
  u32 u = __float_as_uint(f);
  u += 0x7fffu + ((u >> 16) & 1u);
  return (u16)(u >> 16);
}
__device__ inline u32 pack2(float a, float b) {
  return (u32)f2b(a) | ((u32)f2b(b) << 16);
}

__device__ inline void gload16(const void* g, void* l) {
  __builtin_amdgcn_global_load_lds(
      (const __attribute__((address_space(1))) void*)g,
      (__attribute__((address_space(3))) void*)l, 16, 0, 0);
}

// XCD-chunked bijective block map (m204 formula): hardware assigns
// xcd = wg % 8; give each XCD a CONTIGUOUS range of ord = mt*ntn + nt
// (m-major) so its L2 holds one A-chunk + all of B instead of thrashing.
__device__ inline int xcd_ord(int wg, int nwg) {
  int q = nwg >> 3, r = nwg & 7;
  int xcd = wg & 7, k = wg >> 3;
  return xcd * q + min(xcd, r) + k;
}

// ---------------- zero-init (int) ----------------
__global__ void k_zeroi(int* __restrict__ p, int n) {
  int i = blockIdx.x * blockDim.x + threadIdx.x;
  if (i < n) p[i] = 0;
}

// ---------------- fp32 -> bf16 cast (pairs) ----------------
__global__ void k_f2b2(const float* __restrict__ in, u16* __restrict__ out, int npairs) {
  for (int i = blockIdx.x * blockDim.x + threadIdx.x; i < npairs; i += gridDim.x * blockDim.x) {
    float2 v = *(const float2*)(in + 2 * i);
    ((u32*)out)[i] = pack2(v.x, v.y);
  }
}

// ---------------- all weight transposes in one launch ----------------
// W[K x N] fp32 -> WT[N x K] bf16, 5 matrices by blockIdx range
__global__ void k_wt_all(const float* __restrict__ W1, const float* __restrict__ W2,
                         const float* __restrict__ W3, const float* __restrict__ Wmu,
                         const float* __restrict__ Wlv,
                         u16* __restrict__ T1, u16* __restrict__ T2,
                         u16* __restrict__ T3, u16* __restrict__ Tmu,
                         u16* __restrict__ Tlv) {
  int b = blockIdx.x;
  const float* W; u16* T; int K, N;
  if (b < 2048)      { W = W1;  T = T1;  K = 512;  N = 1024; }
  else if (b < 4096) { W = W2;  T = T2;  K = 1024; N = 512;  b -= 2048; }
  else if (b < 4608) { W = W3;  T = T3;  K = 512;  N = 256;  b -= 4096; }
  else if (b < 5120) { W = Wmu; T = Tmu; K = 256;  N = 512;  b -= 4608; }
  else               { W = Wlv; T = Tlv; K = 256;  N = 512;  b -= 5120; }
  int kb = K >> 8;
  int n = b / kb;
  int k = (b % kb) * 256 + threadIdx.x;
  T[(size_t)n * K + k] = f2b(W[(size_t)k * N + n]);
}

// ---------------- CSR build: count / scan / fill ----------------
__global__ void k_count(const int* __restrict__ ei, int* __restrict__ counts) {
  int e = blockIdx.x * blockDim.x + threadIdx.x;
  if (e < EE) atomicAdd(counts + ei[EE + e], 1);
}

__global__ __launch_bounds__(256)
void k_scan(const int* __restrict__ counts, int* __restrict__ rowptr, int* __restrict__ cursor) {
  const int CHUNK = (NN + 255) / 256;
  int t = threadIdx.x;
  int lo = t * CHUNK, hi = min(lo + CHUNK, NN);
  int s = 0;
  for (int i = lo; i < hi; ++i) s += counts[i];
  __shared__ int tsum[256];
  tsum[t] = s;
  __syncthreads();
  if (t == 0) {
    int run = 0;
    for (int i = 0; i < 256; ++i) { int v = tsum[i]; tsum[i] = run; run += v; }
  }
  __syncthreads();
  int run = tsum[t];
  for (int i = lo; i < hi; ++i) {
    rowptr[i] = run;
    cursor[i] = run;
    run += counts[i];
  }
  if (t == 255) rowptr[NN] = EE;
}

__global__ void k_fill(const int* __restrict__ ei, const float* __restrict__ ew,
                       int* __restrict__ cursor, int* __restrict__ colsrc,
                       float* __restrict__ ecw) {
  int e = blockIdx.x * blockDim.x + threadIdx.x;
  if (e < EE) {
    int d = ei[EE + e];
    int pos = atomicAdd(cursor + d, 1);
    colsrc[pos] = ei[e];
    ecw[pos] = ew[e];
  }
}

__global__ void k_degcsr(const int* __restrict__ rowptr, const float* __restrict__ ecw,
                         float* __restrict__ dinv, float* __restrict__ dinv2) {
  int i = blockIdx.x * blockDim.x + threadIdx.x;
  if (i < NN) {
    float s = 0.f;
    for (int e = rowptr[i]; e < rowptr[i + 1]; ++e) s += ecw[e];
    float d = s + 1.0f;
    dinv[i] = rsqrtf(d);
    dinv2[i] = 1.0f / d;
  }
}

// ---------------- bf16 MFMA GEMM: C[M,N] = A[M,K] @ BT[N,K]^T (+bias) ----------------
// 1D grid, XCD-chunked m-major mapping (round 8: FETCH 96->18MB).
// Round 9: 2-phase double-buffered prefetch (T3-min): STAGE(next) issued
// BEFORE compute(cur); ONE barrier per K-step (was 2). Load latency hides
// under the ~300cy ds_read+MFMA phase. Theory: GEMM was latency-bound
// (MfmaUtil 14%, hbm 13% peak) -- each K-step paid full load latency
// serially behind the first barrier.
template <bool STORE_BF16, bool HAS_BIAS>
__global__ __launch_bounds__(256)
void k_mfma(const u16* __restrict__ A, const u16* __restrict__ BT,
            const float* __restrict__ bias, void* __restrict__ C,
            int M, int K, int N) {
  __shared__ u16 Asm[2][128 * 32];
  __shared__ u16 Bsm[2][128 * 32];
  const int tid = threadIdx.x;
  const int ntn = N >> 7;
  int ord = xcd_ord(blockIdx.x, gridDim.x);
  const int m0 = (ord / ntn) * 128;
  const int n0 = (ord % ntn) * 128;
  const int lane = tid & 63;
  const int wave = tid >> 6;
  const int wm = (wave >> 1) * 64;
  const int wn = (wave & 1) * 64;
  const int qm = lane & 15;
  const int quad = lane >> 4;

  f32x4 acc[4][4];
#pragma unroll
  for (int i = 0; i < 4; ++i)
#pragma unroll
    for (int j = 0; j < 4; ++j) acc[i][j] = (f32x4){0.f, 0.f, 0.f, 0.f};

  const int row_s = tid >> 2, kc_s = (tid & 3) * 8;  // staging coords (h-loop adds 64 rows)

  // prologue: stage tile 0 into buffer 0
#pragma unroll
  for (int h = 0; h < 2; ++h) {
    int row = h * 64 + row_s;
    gload16(A + (size_t)(m0 + row) * K + kc_s, Asm[0] + row * 32 + kc_s);
    gload16(BT + (size_t)(n0 + row) * K + kc_s, Bsm[0] + row * 32 + kc_s);
  }
  __syncthreads();  // vmcnt(0) + barrier: tile 0 ready

  const int nk = K >> 5;
  int cur = 0;
  for (int t = 0; t < nk; ++t) {
    if (t + 1 < nk) {
      int k1 = (t + 1) * 32;
#pragma unroll
      for (int h = 0; h < 2; ++h) {
        int row = h * 64 + row_s;
        gload16(A + (size_t)(m0 + row) * K + k1 + kc_s, Asm[cur ^ 1] + row * 32 + kc_s);
        gload16(BT + (size_t)(n0 + row) * K + k1 + kc_s, Bsm[cur ^ 1] + row * 32 + kc_s);
      }
    }
    short8 af[4], bfr[4];
#pragma unroll
    for (int i = 0; i < 4; ++i)
      af[i] = *(const short8*)(Asm[cur] + (wm + i * 16 + qm) * 32 + quad * 8);
#pragma unroll
    for (int j = 0; j < 4; ++j)
      bfr[j] = *(const short8*)(Bsm[cur] + (wn + j * 16 + qm) * 32 + quad * 8);
#pragma unroll
    for (int i = 0; i < 4; ++i)
#pragma unroll
      for (int j = 0; j < 4; ++j)
        acc[i][j] = __builtin_amdgcn_mfma_f32_16x16x32_bf16(af[i], bfr[j], acc[i][j], 0, 0, 0);
    if (t + 1 < nk) {
      __syncthreads();  // drains prefetch (vmcnt(0)) + orders buffer reuse
      cur ^= 1;
    }
  }

#pragma unroll
  for (int i = 0; i < 4; ++i) {
#pragma unroll
    for (int r = 0; r < 4; ++r) {
      int row = m0 + wm + i * 16 + quad * 4 + r;
      if (row >= M) continue;
#pragma unroll
      for (int j = 0; j < 4; ++j) {
        int col = n0 + wn + j * 16 + qm;
        float v = acc[i][j][r];
        if (HAS_BIAS) v += bias[col];
        if (STORE_BF16) ((u16*)C)[(size_t)row * N + col] = f2b(v);
        else ((float*)C)[(size_t)row * N + col] = v;
      }
    }
  }
}

// ---------------- dual-head MFMA + fused z-pooling ----------------
// v2: 128M x 64N tile, __launch_bounds__(256,3); v3: + XCD-chunked map.
__global__ __launch_bounds__(256, 3)
void k_heads(const u16* __restrict__ A, const u16* __restrict__ BmuT,
             const u16* __restrict__ BlvT, const float* __restrict__ bmu,
             const float* __restrict__ blv, const float* __restrict__ eps,
             const float* __restrict__ beta_p, float* __restrict__ mu_out,
             float* __restrict__ lv_out, float* __restrict__ pmax,
             float* __restrict__ psum) {
  const int K = 256;
  __shared__ float smemf[4352];  // 17408 B, aliased across phases
  u16* Asm = (u16*)smemf;                    // [0, 8192)      128x32 bf16
  u16* Bmu = (u16*)((char*)smemf + 8192);    // [8192, 12288)  64x32 bf16
  u16* Blv = (u16*)((char*)smemf + 12288);   // [12288, 16384) 64x32 bf16
  float* stmu = smemf;                       // 32*68 floats = 8704 B
  float* stlv = smemf + 32 * 68;             // [8704, 17408)
  const int tid = threadIdx.x;
  int ord = xcd_ord(blockIdx.x, gridDim.x);
  const int mt = ord >> 3;                   // ntn = 8
  const int m0 = mt * 128;
  const int n0 = (ord & 7) * 64;             // 64-wide N tile
  const int lane = tid & 63;
  const int wave = tid >> 6;
  const int wm = (wave >> 1) * 64;
  const int wn = (wave & 1) * 32;            // 32-wide per wave
  const int qm = lane & 15;
  const int quad = lane >> 4;

  f32x4 am[4][2], al[4][2];
#pragma unroll
  for (int i = 0; i < 4; ++i)
#pragma unroll
    for (int j = 0; j < 2; ++j) {
      am[i][j] = (f32x4){0.f, 0.f, 0.f, 0.f};
      al[i][j] = (f32x4){0.f, 0.f, 0.f, 0.f};
    }

  for (int k0 = 0; k0 < K; k0 += 32) {
    // A tile: 128x32 = 8192 B -> 2 gload16/thread
#pragma unroll
    for (int h = 0; h < 2; ++h) {
      int c = h * 256 + tid;
      int row = c >> 2, kc = c & 3;
      gload16(A + (size_t)(m0 + row) * K + k0 + kc * 8, Asm + c * 8);
    }
    // B tiles: 64x32 = 4096 B each -> 1 gload16/thread each
    {
      int row = tid >> 2, kc = tid & 3;
      gload16(BmuT + (size_t)(n0 + row) * K + k0 + kc * 8, Bmu + tid * 8);
      gload16(BlvT + (size_t)(n0 + row) * K + k0 + kc * 8, Blv + tid * 8);
    }
    __syncthreads();
    short8 af[4], bm[2], bl[2];
#pragma unroll
    for (int i = 0; i < 4; ++i)
      af[i] = *(const short8*)(Asm + (wm + i * 16 + qm) * 32 + quad * 8);
#pragma unroll
    for (int j = 0; j < 2; ++j) {
      bm[j] = *(const short8*)(Bmu + (wn + j * 16 + qm) * 32 + quad * 8);
      bl[j] = *(const short8*)(Blv + (wn + j * 16 + qm) * 32 + quad * 8);
    }
#pragma unroll
    for (int i = 0; i < 4; ++i)
#pragma unroll
      for (int j = 0; j < 2; ++j) {
        am[i][j] = __builtin_amdgcn_mfma_f32_16x16x32_bf16(af[i], bm[j], am[i][j], 0, 0, 0);
        al[i][j] = __builtin_amdgcn_mfma_f32_16x16x32_bf16(af[i], bl[j], al[i][j], 0, 0, 0);
      }
    __syncthreads();
  }

  const float beta = beta_p[0];
  float biasm[2], biasl[2];
#pragma unroll
  for (int j = 0; j < 2; ++j) {
    int col = n0 + wn + j * 16 + qm;
    biasm[j] = bmu[col];
    biasl[j] = blv[col];
  }

  // per-thread pool partials over 8 fixed columns
  float zmax[8], zsum[8];
#pragma unroll
  for (int q = 0; q < 8; ++q) { zmax[q] = -3.4e38f; zsum[q] = 0.f; }
  const int lrow_r = tid >> 3;        // 0..31
  const int colb = (tid & 7) * 8;     // 0..56

  for (int c = 0; c < 4; ++c) {
    __syncthreads();
    if ((wave >> 1) == (c >> 1)) {
      int ibase = (c & 1) * 2;
#pragma unroll
      for (int ii = 0; ii < 2; ++ii) {
        int i = ibase + ii;
#pragma unroll
        for (int j = 0; j < 2; ++j) {
          int lcol = wn + j * 16 + qm;
#pragma unroll
          for (int r = 0; r < 4; ++r) {
            int lr = ii * 16 + quad * 4 + r;
            stmu[lr * 68 + lcol] = am[i][j][r] + biasm[j];
            stlv[lr * 68 + lcol] = al[i][j][r] + biasl[j];
          }
        }
      }
    }
    __syncthreads();
    int grow = m0 + c * 32 + lrow_r;
    if (grow < NN) {
#pragma unroll
      for (int q4 = 0; q4 < 2; ++q4) {
        int lcol = colb + q4 * 4;
        float4 m4 = *(float4*)(stmu + lrow_r * 68 + lcol);
        float4 l4 = *(float4*)(stlv + lrow_r * 68 + lcol);
        size_t gidx = (size_t)grow * 512 + n0 + lcol;
        float4 e4 = *(const float4*)(eps + gidx);
        *(float4*)(mu_out + gidx) = m4;
        *(float4*)(lv_out + gidx) = l4;
        float z0 = m4.x + 0.01f * e4.x * expf(0.5f * beta * l4.x);
        float z1 = m4.y + 0.01f * e4.y * expf(0.5f * beta * l4.y);
        float z2 = m4.z + 0.01f * e4.z * expf(0.5f * beta * l4.z);
        float z3 = m4.w + 0.01f * e4.w * expf(0.5f * beta * l4.w);
        zmax[q4 * 4 + 0] = fmaxf(zmax[q4 * 4 + 0], z0); zsum[q4 * 4 + 0] += z0;
        zmax[q4 * 4 + 1] = fmaxf(zmax[q4 * 4 + 1], z1); zsum[q4 * 4 + 1] += z1;
        zmax[q4 * 4 + 2] = fmaxf(zmax[q4 * 4 + 2], z2); zsum[q4 * 4 + 2] += z2;
        zmax[q4 * 4 + 3] = fmaxf(zmax[q4 * 4 + 3], z3); zsum[q4 * 4 + 3] += z3;
      }
    }
  }

  // pool reduction: 32 threads (lrow groups) share each 8-col group
  __syncthreads();
  float* rbuf = smemf;  // 256*16 floats = 16384 B
#pragma unroll
  for (int q = 0; q < 8; ++q) {
    rbuf[tid * 16 + q] = zmax[q];
    rbuf[tid * 16 + 8 + q] = zsum[q];
  }
  __syncthreads();
  if (tid < 64) {
    int g = tid >> 3, o = tid & 7;   // col = g*8+o = tid
    float m = -3.4e38f, s = 0.f;
    for (int k = 0; k < 32; ++k) {
      int src = (k * 8 + g) * 16;
      m = fmaxf(m, rbuf[src + o]);
      s += rbuf[src + 8 + o];
    }
    pmax[(size_t)mt * 512 + n0 + tid] = m;
    psum[(size_t)mt * 512 + n0 + tid] = s;
  }
}

// rz[1025] = [max-pool | mean-pool | y_target], reducing MTILES partials
__global__ void k_zred(const float* __restrict__ pmax, const float* __restrict__ psum,
                       const float* __restrict__ yt, float* __restrict__ rz) {
  int col = threadIdx.x;  // 512 threads
  float m = -3.4e38f, s = 0.f;
  for (int c = 0; c < MTILES; ++c) {
    m = fmaxf(m, pmax[(size_t)c * 512 + col]);
    s += psum[(size_t)c * 512 + col];
  }
  rz[col] = m;
  rz[512 + col] = s / (float)NN;
  if (col == 0) rz[1024] = yt[0];
}

// ---------------- fused CSR gather (bf16 in/out), vectorized: O = 4*NT ----------------
template <int NT, bool PRE>
__global__ __launch_bounds__(NT)
void k_gatherv(const int* __restrict__ rowptr, const int* __restrict__ colsrc,
               const float* __restrict__ ecw, const float* __restrict__ dinv,
               const float* __restrict__ dinv2, const u16* __restrict__ xw,
               const float* __restrict__ bias, u16* __restrict__ h) {
  const int O = 4 * NT;
  const int row = blockIdx.x;
  const int tid = threadIdx.x;
  const float dv = dinv[row], dv2 = dinv2[row];
  uint2 u = ((const uint2*)(xw + (size_t)row * O))[tid];
  float a0 = dv2 * bf16lo(u.x), a1 = dv2 * bf16hi(u.x);
  float a2 = dv2 * bf16lo(u.y), a3 = dv2 * bf16hi(u.y);
  if (!PRE) {
    a0 += bias[4 * tid];     a1 += bias[4 * tid + 1];
    a2 += bias[4 * tid + 2]; a3 += bias[4 * tid + 3];
  }
  float c0 = 0.f, c1 = 0.f, c2 = 0.f, c3 = 0.f;

  __shared__ int s_src[NT];
  __shared__ float s_w[NT];
  const int e0 = rowptr[row], e1 = rowptr[row + 1];
  for (int base = e0; base < e1; base += NT) {
    int cnt = min(NT, e1 - base);
    __syncthreads();
    if (tid < cnt) {
      int s = colsrc[base + tid];
      s_src[tid] = s;
      s_w[tid] = dinv[s] * ecw[base + tid] * dv;
    }
    __syncthreads();
    int e = 0;
    for (; e + 2 <= cnt; e += 2) {
      float w0 = s_w[e], w1 = s_w[e + 1];
      uint2 v0 = ((const uint2*)(xw + (size_t)s_src[e] * O))[tid];
      uint2 v1 = ((const uint2*)(xw + (size_t)s_src[e + 1] * O))[tid];
      a0 += w0 * bf16lo(v0.x); a1 += w0 * bf16hi(v0.x);
      a2 += w0 * bf16lo(v0.y); a3 += w0 * bf16hi(v0.y);
      c0 += w1 * bf16lo(v1.x); c1 += w1 * bf16hi(v1.x);
      c2 += w1 * bf16lo(v1.y); c3 += w1 * bf16hi(v1.y);
    }
    if (e < cnt) {
      float w = s_w[e];
      uint2 v = ((const uint2*)(xw + (size_t)s_src[e] * O))[tid];
      a0 += w * bf16lo(v.x); a1 += w * bf16hi(v.x);
      a2 += w * bf16lo(v.y); a3 += w * bf16hi(v.y);
    }
  }
  a0 += c0; a1 += c1; a2 += c2; a3 += c3;

  if (PRE) {
    uint2 o; o.x = pack2(a0, a1); o.y = pack2(a2, a3);
    ((uint2*)(h + (size_t)row * O))[tid] = o;
    return;
  }
  float ss = a0 * a0 + a1 * a1 + a2 * a2 + a3 * a3;
#pragma unroll
  for (int off = 32; off > 0; off >>= 1) ss += __shfl_down(ss, off, 64);
  __shared__ float red[(NT + 63) / 64];
  __shared__ float s_scale;
  if ((tid & 63) == 0) red[tid >> 6] = ss;
  __syncthreads();
  if (tid == 0) {
    float t = 0.f;
#pragma unroll
    for (int i = 0; i < (NT + 63) / 64; ++i) t += red[i];
    s_scale = 1.0f / fmaxf(sqrtf(t), 1e-12f);
  }
  __syncthreads();
  float sc = s_scale;
  uint2 o;
  o.x = pack2(fmaxf(a0 * sc, 0.f), fmaxf(a1 * sc, 0.f));
  o.y = pack2(fmaxf(a2 * sc, 0.f), fmaxf(a3 * sc, 0.f));
  ((uint2*)(h + (size_t)row * O))[tid] = o;
}

// ---------------- rowwise l2norm + relu, bf16 in/out, O=1024 ----------------
__global__ __launch_bounds__(256)
void k_l2relu(const u16* __restrict__ t, u16* __restrict__ h) {
  const int row = blockIdx.x;
  const int tid = threadIdx.x;
  const u32* tr = (const u32*)(t + (size_t)row * 1024);
  u32 u0 = tr[tid], u1 = tr[256 + tid];
  float a0 = bf16lo(u0), a1 = bf16hi(u0), a2 = bf16lo(u1), a3 = bf16hi(u1);
  float ss = a0 * a0 + a1 * a1 + a2 * a2 + a3 * a3;
#pragma unroll
  for (int off = 32; off > 0; off >>= 1) ss += __shfl_down(ss, off, 64);
  __shared__ float red[4];
  __shared__ float s_scale;
  if ((tid & 63) == 0) red[tid >> 6] = ss;
  __syncthreads();
  if (tid == 0) {
    float s = red[0] + red[1] + red[2] + red[3];
    s_scale = 1.0f / fmaxf(sqrtf(s), 1e-12f);
  }
  __syncthreads();
  float sc = s_scale;
  u32* hr = (u32*)(h + (size_t)row * 1024);
  hr[tid]       = pack2(fmaxf(a0 * sc, 0.f), fmaxf(a1 * sc, 0.f));
  hr[256 + tid] = pack2(fmaxf(a2 * sc, 0.f), fmaxf(a3 * sc, 0.f));
}

// ---------------- parallel decoder ----------------
__global__ __launch_bounds__(256)
void k_dec_partial(const float* __restrict__ v, const float* __restrict__ W,
                   float* __restrict__ partial, int Kdim, int Ndim) {
  int b = blockIdx.x;
  int lo = b * DCH;
  float rv[DCH];
#pragma unroll
  for (int j = 0; j < DCH; ++j) rv[j] = (lo + j < Kdim) ? v[lo + j] : 0.f;
  for (int n = threadIdx.x; n < Ndim; n += 256) {
    float s = 0.f;
#pragma unroll
    for (int j = 0; j < DCH; ++j)
      if (lo + j < Kdim) s += rv[j] * W[(size_t)(lo + j) * Ndim + n];
    partial[(size_t)b * Ndim + n] = s;
  }
}

template <int ACT>
__global__ __launch_bounds__(256)
void k_dec_combine(const float* __restrict__ partial, const float* __restrict__ bias,
                   float* __restrict__ out, int Ndim) {
  int n = blockIdx.x * 256 + threadIdx.x;
  if (n >= Ndim) return;
  float s = bias[n];
  for (int b = 0; b < DKB; ++b) s += partial[(size_t)b * Ndim + n];
  out[n] = (ACT == 0) ? fmaxf(s, 0.f) : 1.0f / (1.0f + expf(-s));
}

extern "C" void kernel_launch(void* const* d_in, const int* in_sizes, int n_in,
                              void* d_out, int out_size, void* d_ws, size_t ws_size,
                              hipStream_t stream) {
  const float* x    = (const float*)d_in[0];
  const int*   ei   = (const int*)d_in[1];
  const float* ew   = (const float*)d_in[2];
  const float* beta = (const float*)d_in[3];
  const float* yt   = (const float*)d_in[4];
  const float* eps  = (const float*)d_in[5];
  const float* W1   = (const float*)d_in[6];  const float* b1  = (const float*)d_in[7];
  const float* W2   = (const float*)d_in[8];  const float* b2  = (const float*)d_in[9];
  const float* W3   = (const float*)d_in[10]; const float* b3  = (const float*)d_in[11];
  const float* Wmu  = (const float*)d_in[12]; const float* bmu = (const float*)d_in[13];
  const float* Wlv  = (const float*)d_in[14]; const float* blv = (const float*)d_in[15];
  const float* Wd1  = (const float*)d_in[16]; const float* bd1 = (const float*)d_in[17];
  const float* Wd2  = (const float*)d_in[18]; const float* bd2 = (const float*)d_in[19];

  char* wsb = (char*)d_ws;
  size_t off = 0;
  // 16B-aligned workspace allocs (uint2 / dwordx4 natural alignment)
  auto alloc_f = [&](size_t n) { float* p = (float*)(wsb + off); off += ((n * sizeof(float) + 15) & ~(size_t)15); return p; };
  auto alloc_i = [&](size_t n) { int* p = (int*)(wsb + off); off += ((n * sizeof(int) + 15) & ~(size_t)15); return p; };
  auto alloc_h = [&](size_t n) { u16* p = (u16*)(wsb + off); off += ((n * 2 + 15) & ~(size_t)15); return p; };

  int* counts  = alloc_i(NN);
  int* rowptr  = alloc_i(NN + 1);
  int* cursor  = alloc_i(NN);
  int* colsrc  = alloc_i(EE);
  float* ecw   = alloc_f(EE);
  float* dinv  = alloc_f(NN);
  float* din2  = alloc_f(NN);
  float* pmax  = alloc_f((size_t)MTILES * 512);
  float* psum  = alloc_f((size_t)MTILES * 512);
  float* rz    = alloc_f(1028);
  float* hdec  = alloc_f(1028);
  float* part1 = alloc_f((size_t)DKB * 1025);
  float* part2 = alloc_f((size_t)DKB * 1024);
  u16* W1T  = alloc_h(1024 * 512);
  u16* W2T  = alloc_h(512 * 1024);
  u16* W3T  = alloc_h(256 * 512);
  u16* WmuT = alloc_h(512 * 256);
  u16* WlvT = alloc_h(512 * 256);
  u16* xb   = alloc_h((size_t)MPAD * 512);   // x bf16; later reused as h3 (256)
  u16* aggx = alloc_h((size_t)MPAD * 512);   // pre-aggregated x
  u16* bufT = alloc_h((size_t)MPAD * 1024);  // t1; later z2 (512)
  u16* bufH = alloc_h((size_t)MPAD * 1024);  // h1; later z3 (256)
  u16* h2   = alloc_h((size_t)MPAD * 512);
  u16* h3   = xb;
  u16* z2   = bufT;
  u16* z3   = bufH;

  float* out_f  = (float*)d_out;
  float* mu_out = out_f + 1024;
  float* lv_out = out_f + 1024 + (size_t)NN * 512;

  const int MT = MTILES;

  // ---- casts / transposes ----
  k_f2b2<<<4096, 256, 0, stream>>>(x, xb, NN * 512 / 2);
  k_wt_all<<<5632, 256, 0, stream>>>(W1, W2, W3, Wmu, Wlv, W1T, W2T, W3T, WmuT, WlvT);

  // ---- CSR build + degree norms ----
  k_zeroi<<<(NN + 255) / 256, 256, 0, stream>>>(counts, NN);
  k_count<<<(EE + 255) / 256, 256, 0, stream>>>(ei, counts);
  k_scan<<<1, 256, 0, stream>>>(counts, rowptr, cursor);
  k_fill<<<(EE + 255) / 256, 256, 0, stream>>>(ei, ew, cursor, colsrc, ecw);
  k_degcsr<<<(NN + 255) / 256, 256, 0, stream>>>(rowptr, ecw, dinv, din2);

  // ---- layer 1: aggregate x first (linearity), then GEMM+bias, then l2relu ----
  k_gatherv<128, true><<<NN, 128, 0, stream>>>(rowptr, colsrc, ecw, dinv, din2, xb, nullptr, aggx);
  k_mfma<true, true><<<MT * 8, 256, 0, stream>>>(aggx, W1T, b1, bufT, NN, 512, 1024);
  k_l2relu<<<NN, 256, 0, stream>>>(bufT, bufH);

  // ---- layer 2: GEMM then fused gather+bias+l2relu ----
  k_mfma<true, false><<<MT * 4, 256, 0, stream>>>(bufH, W2T, nullptr, z2, NN, 1024, 512);
  k_gatherv<128, false><<<NN, 128, 0, stream>>>(rowptr, colsrc, ecw, dinv, din2, z2, b2, h2);

  // ---- layer 3 ----
  k_mfma<true, false><<<MT * 2, 256, 0, stream>>>(h2, W3T, nullptr, z3, NN, 512, 256);
  k_gatherv<64, false><<<NN, 64, 0, stream>>>(rowptr, colsrc, ecw, dinv, din2, z3, b3, h3);

  // ---- fused VAE heads + reparameterize + partial pooling (64-wide N tiles) ----
  k_heads<<<MT * 8, 256, 0, stream>>>(h3, WmuT, WlvT, bmu, blv, eps, beta,
                                      mu_out, lv_out, pmax, psum);
  k_zred<<<1, 512, 0, stream>>>(pmax, psum, yt, rz);

  // ---- parallel decoder ----
  k_dec_partial<<<DKB, 256, 0, stream>>>(rz, Wd1, part1, 1025, 1025);
  k_dec_combine<0><<<5, 256, 0, stream>>>(part1, bd1, hdec, 1025);
  k_dec_partial<<<DKB, 256, 0, stream>>>(hdec, Wd2, part2, 1025, 1024);
  k_dec_combine<1><<<4, 256, 0, stream>>>(part2, bd2, out_f, 1024);
}

// Round 11
// 637.505 us; speedup vs baseline: 1.0685x; 1.0057x over previous
//
#include <hip/hip_runtime.h>

#define NN 20000
#define EE 320000
#define MPAD 20096   // NN padded to multiple of 128
#define MTILES 157   // ceil(NN/128)
#define DKB 128      // decoder partial blocks
#define DCH 9        // ceil(1025/128)

typedef unsigned short u16;
typedef unsigned int u32;
typedef __attribute__((ext_vector_type(8))) short short8;
typedef __attribute__((ext_vector_type(4))) float f32x4;

// ---------------- bf16 helpers ----------------
__device__ inline float bf16lo(u32 u) { return __uint_as_float(u << 16); }
__device__ inline float bf16hi(u32 u) { return __uint_as_float(u & 0xffff0000u); }
__device__ inline u16 f2b(float f) {
  u32 u = __float_as_uint(f);
  u += 0x7fffu + ((u >> 16) & 1u);
  return (u16)(u >> 16);
}
__device__ inline u32 pack2(float a, float b) {
  return (u32)f2b(a) | ((u32)f2b(b) << 16);
}

__device__ inline void gload16(const void* g, void* l) {
  __builtin_amdgcn_global_load_lds(
      (const __attribute__((address_space(1))) void*)g,
      (__attribute__((address_space(3))) void*)l, 16, 0, 0);
}

// XCD-chunked bijective block map (m204 formula)
__device__ inline int xcd_ord(int wg, int nwg) {
  int q = nwg >> 3, r = nwg & 7;
  int xcd = wg & 7, k = wg >> 3;
  return xcd * q + min(xcd, r) + k;
}

// ---------------- zero-init (int) ----------------
__global__ void k_zeroi(int* __restrict__ p, int n) {
  int i = blockIdx.x * blockDim.x + threadIdx.x;
  if (i < n) p[i] = 0;
}

// ---------------- fp32 -> bf16 cast (pairs) ----------------
__global__ void k_f2b2(const float* __restrict__ in, u16* __restrict__ out, int npairs) {
  for (int i = blockIdx.x * blockDim.x + threadIdx.x; i < npairs; i += gridDim.x * blockDim.x) {
    float2 v = *(const float2*)(in + 2 * i);
    ((u32*)out)[i] = pack2(v.x, v.y);
  }
}

// ---------------- all weight transposes in one launch ----------------
__global__ void k_wt_all(const float* __restrict__ W1, const float* __restrict__ W2,
                         const float* __restrict__ W3, const float* __restrict__ Wmu,
                         const float* __restrict__ Wlv,
                         u16* __restrict__ T1, u16* __restrict__ T2,
                         u16* __restrict__ T3, u16* __restrict__ Tmu,
                         u16* __restrict__ Tlv) {
  int b = blockIdx.x;
  const float* W; u16* T; int K, N;
  if (b < 2048)      { W = W1;  T = T1;  K = 512;  N = 1024; }
  else if (b < 4096) { W = W2;  T = T2;  K = 1024; N = 512;  b -= 2048; }
  else if (b < 4608) { W = W3;  T = T3;  K = 512;  N = 256;  b -= 4096; }
  else if (b < 5120) { W = Wmu; T = Tmu; K = 256;  N = 512;  b -= 4608; }
  else               { W = Wlv; T = Tlv; K = 256;  N = 512;  b -= 5120; }
  int kb = K >> 8;
  int n = b / kb;
  int k = (b % kb) * 256 + threadIdx.x;
  T[(size_t)n * K + k] = f2b(W[(size_t)k * N + n]);
}

// ---------------- CSR build: count / scan / fill ----------------
__global__ void k_count(const int* __restrict__ ei, int* __restrict__ counts) {
  int e = blockIdx.x * blockDim.x + threadIdx.x;
  if (e < EE) atomicAdd(counts + ei[EE + e], 1);
}

__global__ __launch_bounds__(256)
void k_scan(const int* __restrict__ counts, int* __restrict__ rowptr, int* __restrict__ cursor) {
  const int CHUNK = (NN + 255) / 256;
  int t = threadIdx.x;
  int lo = t * CHUNK, hi = min(lo + CHUNK, NN);
  int s = 0;
  for (int i = lo; i < hi; ++i) s += counts[i];
  __shared__ int tsum[256];
  tsum[t] = s;
  __syncthreads();
  if (t == 0) {
    int run = 0;
    for (int i = 0; i < 256; ++i) { int v = tsum[i]; tsum[i] = run; run += v; }
  }
  __syncthreads();
  int run = tsum[t];
  for (int i = lo; i < hi; ++i) {
    rowptr[i] = run;
    cursor[i] = run;
    run += counts[i];
  }
  if (t == 255) rowptr[NN] = EE;
}

__global__ void k_fill(const int* __restrict__ ei, const float* __restrict__ ew,
                       int* __restrict__ cursor, int* __restrict__ colsrc,
                       float* __restrict__ ecw) {
  int e = blockIdx.x * blockDim.x + threadIdx.x;
  if (e < EE) {
    int d = ei[EE + e];
    int pos = atomicAdd(cursor + d, 1);
    colsrc[pos] = ei[e];
    ecw[pos] = ew[e];
  }
}

__global__ void k_degcsr(const int* __restrict__ rowptr, const float* __restrict__ ecw,
                         float* __restrict__ dinv, float* __restrict__ dinv2) {
  int i = blockIdx.x * blockDim.x + threadIdx.x;
  if (i < NN) {
    float s = 0.f;
    for (int e = rowptr[i]; e < rowptr[i + 1]; ++e) s += ecw[e];
    float d = s + 1.0f;
    dinv[i] = rsqrtf(d);
    dinv2[i] = 1.0f / d;
  }
}

// ---------------- bf16 MFMA GEMM: C[M,N] = A[M,K] @ BT[N,K]^T (+bias) ----------------
// XCD-chunked map + 2-phase double-buffered prefetch (rounds 8/9).
template <bool STORE_BF16, bool HAS_BIAS>
__global__ __launch_bounds__(256)
void k_mfma(const u16* __restrict__ A, const u16* __restrict__ BT,
            const float* __restrict__ bias, void* __restrict__ C,
            int M, int K, int N) {
  __shared__ u16 Asm[2][128 * 32];
  __shared__ u16 Bsm[2][128 * 32];
  const int tid = threadIdx.x;
  const int ntn = N >> 7;
  int ord = xcd_ord(blockIdx.x, gridDim.x);
  const int m0 = (ord / ntn) * 128;
  const int n0 = (ord % ntn) * 128;
  const int lane = tid & 63;
  const int wave = tid >> 6;
  const int wm = (wave >> 1) * 64;
  const int wn = (wave & 1) * 64;
  const int qm = lane & 15;
  const int quad = lane >> 4;

  f32x4 acc[4][4];
#pragma unroll
  for (int i = 0; i < 4; ++i)
#pragma unroll
    for (int j = 0; j < 4; ++j) acc[i][j] = (f32x4){0.f, 0.f, 0.f, 0.f};

  const int row_s = tid >> 2, kc_s = (tid & 3) * 8;

  // prologue: stage tile 0 into buffer 0
#pragma unroll
  for (int h = 0; h < 2; ++h) {
    int row = h * 64 + row_s;
    gload16(A + (size_t)(m0 + row) * K + kc_s, Asm[0] + row * 32 + kc_s);
    gload16(BT + (size_t)(n0 + row) * K + kc_s, Bsm[0] + row * 32 + kc_s);
  }
  __syncthreads();

  const int nk = K >> 5;
  int cur = 0;
  for (int t = 0; t < nk; ++t) {
    if (t + 1 < nk) {
      int k1 = (t + 1) * 32;
#pragma unroll
      for (int h = 0; h < 2; ++h) {
        int row = h * 64 + row_s;
        gload16(A + (size_t)(m0 + row) * K + k1 + kc_s, Asm[cur ^ 1] + row * 32 + kc_s);
        gload16(BT + (size_t)(n0 + row) * K + k1 + kc_s, Bsm[cur ^ 1] + row * 32 + kc_s);
      }
    }
    short8 af[4], bfr[4];
#pragma unroll
    for (int i = 0; i < 4; ++i)
      af[i] = *(const short8*)(Asm[cur] + (wm + i * 16 + qm) * 32 + quad * 8);
#pragma unroll
    for (int j = 0; j < 4; ++j)
      bfr[j] = *(const short8*)(Bsm[cur] + (wn + j * 16 + qm) * 32 + quad * 8);
#pragma unroll
    for (int i = 0; i < 4; ++i)
#pragma unroll
      for (int j = 0; j < 4; ++j)
        acc[i][j] = __builtin_amdgcn_mfma_f32_16x16x32_bf16(af[i], bfr[j], acc[i][j], 0, 0, 0);
    if (t + 1 < nk) {
      __syncthreads();
      cur ^= 1;
    }
  }

#pragma unroll
  for (int i = 0; i < 4; ++i) {
#pragma unroll
    for (int r = 0; r < 4; ++r) {
      int row = m0 + wm + i * 16 + quad * 4 + r;
      if (row >= M) continue;
#pragma unroll
      for (int j = 0; j < 4; ++j) {
        int col = n0 + wn + j * 16 + qm;
        float v = acc[i][j][r];
        if (HAS_BIAS) v += bias[col];
        if (STORE_BF16) ((u16*)C)[(size_t)row * N + col] = f2b(v);
        else ((float*)C)[(size_t)row * N + col] = v;
      }
    }
  }
}

// ---------------- dual-head MFMA + fused z-pooling ----------------
// v4: 2-phase double-buffered K-loop (one barrier/step) + eps register
// prefetch issued before the epilogue barriers (T14 issue-early).
// Theory: v3 was latency-bound (MfmaUtil 6%, hbm 30% achievable) -- K-loop
// paid serial load latency x8 and each epilogue chunk stalled on its eps read.
__global__ __launch_bounds__(256, 3)
void k_heads(const u16* __restrict__ A, const u16* __restrict__ BmuT,
             const u16* __restrict__ BlvT, const float* __restrict__ bmu,
             const float* __restrict__ blv, const float* __restrict__ eps,
             const float* __restrict__ beta_p, float* __restrict__ mu_out,
             float* __restrict__ lv_out, float* __restrict__ pmax,
             float* __restrict__ psum) {
  const int K = 256;
  __shared__ char smem[32768];
  u16* AsmD[2] = {(u16*)smem, (u16*)(smem + 8192)};                    // 2x 128x32
  u16* BmuD[2] = {(u16*)(smem + 16384), (u16*)(smem + 20480)};         // 2x 64x32
  u16* BlvD[2] = {(u16*)(smem + 24576), (u16*)(smem + 28672)};         // 2x 64x32
  float* stmu = (float*)smem;                 // 32*68 floats = 8704 B (aliased)
  float* stlv = (float*)(smem + 8704);        // [8704, 17408)
  float* rbuf = (float*)smem;                 // 256*16 floats = 16384 B (aliased)
  const int tid = threadIdx.x;
  int ord = xcd_ord(blockIdx.x, gridDim.x);
  const int mt = ord >> 3;                   // ntn = 8
  const int m0 = mt * 128;
  const int n0 = (ord & 7) * 64;             // 64-wide N tile
  const int lane = tid & 63;
  const int wave = tid >> 6;
  const int wm = (wave >> 1) * 64;
  const int wn = (wave & 1) * 32;            // 32-wide per wave
  const int qm = lane & 15;
  const int quad = lane >> 4;

  f32x4 am[4][2], al[4][2];
#pragma unroll
  for (int i = 0; i < 4; ++i)
#pragma unroll
    for (int j = 0; j < 2; ++j) {
      am[i][j] = (f32x4){0.f, 0.f, 0.f, 0.f};
      al[i][j] = (f32x4){0.f, 0.f, 0.f, 0.f};
    }

  const int rowA = tid >> 2, kcA = (tid & 3) * 8;  // A staging (h adds 64 rows)
  // prologue: stage K-tile 0 into buffer 0
#pragma unroll
  for (int h = 0; h < 2; ++h) {
    int row = h * 64 + rowA;
    gload16(A + (size_t)(m0 + row) * K + kcA, AsmD[0] + row * 32 + kcA);
  }
  gload16(BmuT + (size_t)(n0 + rowA) * K + kcA, BmuD[0] + tid * 8);
  gload16(BlvT + (size_t)(n0 + rowA) * K + kcA, BlvD[0] + tid * 8);
  __syncthreads();

  int cur = 0;
  for (int t = 0; t < 8; ++t) {            // K=256, BK=32
    if (t < 7) {
      int k1 = (t + 1) * 32;
#pragma unroll
      for (int h = 0; h < 2; ++h) {
        int row = h * 64 + rowA;
        gload16(A + (size_t)(m0 + row) * K + k1 + kcA, AsmD[cur ^ 1] + row * 32 + kcA);
      }
      gload16(BmuT + (size_t)(n0 + rowA) * K + k1 + kcA, BmuD[cur ^ 1] + tid * 8);
      gload16(BlvT + (size_t)(n0 + rowA) * K + k1 + kcA, BlvD[cur ^ 1] + tid * 8);
    }
    short8 af[4], bm[2], bl[2];
#pragma unroll
    for (int i = 0; i < 4; ++i)
      af[i] = *(const short8*)(AsmD[cur] + (wm + i * 16 + qm) * 32 + quad * 8);
#pragma unroll
    for (int j = 0; j < 2; ++j) {
      bm[j] = *(const short8*)(BmuD[cur] + (wn + j * 16 + qm) * 32 + quad * 8);
      bl[j] = *(const short8*)(BlvD[cur] + (wn + j * 16 + qm) * 32 + quad * 8);
    }
#pragma unroll
    for (int i = 0; i < 4; ++i)
#pragma unroll
      for (int j = 0; j < 2; ++j) {
        am[i][j] = __builtin_amdgcn_mfma_f32_16x16x32_bf16(af[i], bm[j], am[i][j], 0, 0, 0);
        al[i][j] = __builtin_amdgcn_mfma_f32_16x16x32_bf16(af[i], bl[j], al[i][j], 0, 0, 0);
      }
    if (t < 7) {
      __syncthreads();
      cur ^= 1;
    }
  }

  const float beta = beta_p[0];
  float biasm[2], biasl[2];
#pragma unroll
  for (int j = 0; j < 2; ++j) {
    int col = n0 + wn + j * 16 + qm;
    biasm[j] = bmu[col];
    biasl[j] = blv[col];
  }

  const int lrow_r = tid >> 3;        // 0..31
  const int colb = (tid & 7) * 8;     // 0..56

  // eps register prefetch: issue ALL epilogue eps loads now; HBM latency
  // hides under the LDS transposes below. Static indexing (full unroll).
  float4 e4pre[4][2];
#pragma unroll
  for (int c = 0; c < 4; ++c) {
    int grow = m0 + c * 32 + lrow_r;
    if (grow < NN) {
#pragma unroll
      for (int q4 = 0; q4 < 2; ++q4) {
        size_t gidx = (size_t)grow * 512 + n0 + colb + q4 * 4;
        e4pre[c][q4] = *(const float4*)(eps + gidx);
      }
    }
  }

  float zmax[8], zsum[8];
#pragma unroll
  for (int q = 0; q < 8; ++q) { zmax[q] = -3.4e38f; zsum[q] = 0.f; }

#pragma unroll
  for (int c = 0; c < 4; ++c) {
    __syncthreads();   // c=0: also orders last K-tile reads before stmu overwrite
    if ((wave >> 1) == (c >> 1)) {
      int ibase = (c & 1) * 2;
#pragma unroll
      for (int ii = 0; ii < 2; ++ii) {
        int i = ibase + ii;
#pragma unroll
        for (int j = 0; j < 2; ++j) {
          int lcol = wn + j * 16 + qm;
#pragma unroll
          for (int r = 0; r < 4; ++r) {
            int lr = ii * 16 + quad * 4 + r;
            stmu[lr * 68 + lcol] = am[i][j][r] + biasm[j];
            stlv[lr * 68 + lcol] = al[i][j][r] + biasl[j];
          }
        }
      }
    }
    __syncthreads();
    int grow = m0 + c * 32 + lrow_r;
    if (grow < NN) {
#pragma unroll
      for (int q4 = 0; q4 < 2; ++q4) {
        int lcol = colb + q4 * 4;
        float4 m4 = *(float4*)(stmu + lrow_r * 68 + lcol);
        float4 l4 = *(float4*)(stlv + lrow_r * 68 + lcol);
        size_t gidx = (size_t)grow * 512 + n0 + lcol;
        float4 e4 = e4pre[c][q4];
        *(float4*)(mu_out + gidx) = m4;
        *(float4*)(lv_out + gidx) = l4;
        float z0 = m4.x + 0.01f * e4.x * expf(0.5f * beta * l4.x);
        float z1 = m4.y + 0.01f * e4.y * expf(0.5f * beta * l4.y);
        float z2 = m4.z + 0.01f * e4.z * expf(0.5f * beta * l4.z);
        float z3 = m4.w + 0.01f * e4.w * expf(0.5f * beta * l4.w);
        zmax[q4 * 4 + 0] = fmaxf(zmax[q4 * 4 + 0], z0); zsum[q4 * 4 + 0] += z0;
        zmax[q4 * 4 + 1] = fmaxf(zmax[q4 * 4 + 1], z1); zsum[q4 * 4 + 1] += z1;
        zmax[q4 * 4 + 2] = fmaxf(zmax[q4 * 4 + 2], z2); zsum[q4 * 4 + 2] += z2;
        zmax[q4 * 4 + 3] = fmaxf(zmax[q4 * 4 + 3], z3); zsum[q4 * 4 + 3] += z3;
      }
    }
  }

  // pool reduction: 32 threads (lrow groups) share each 8-col group
  __syncthreads();
#pragma unroll
  for (int q = 0; q < 8; ++q) {
    rbuf[tid * 16 + q] = zmax[q];
    rbuf[tid * 16 + 8 + q] = zsum[q];
  }
  __syncthreads();
  if (tid < 64) {
    int g = tid >> 3, o = tid & 7;   // col = g*8+o = tid
    float m = -3.4e38f, s = 0.f;
    for (int k = 0; k < 32; ++k) {
      int src = (k * 8 + g) * 16;
      m = fmaxf(m, rbuf[src + o]);
      s += rbuf[src + 8 + o];
    }
    pmax[(size_t)mt * 512 + n0 + tid] = m;
    psum[(size_t)mt * 512 + n0 + tid] = s;
  }
}

// rz[1025] = [max-pool | mean-pool | y_target], reducing MTILES partials
__global__ void k_zred(const float* __restrict__ pmax, const float* __restrict__ psum,
                       const float* __restrict__ yt, float* __restrict__ rz) {
  int col = threadIdx.x;  // 512 threads
  float m = -3.4e38f, s = 0.f;
  for (int c = 0; c < MTILES; ++c) {
    m = fmaxf(m, pmax[(size_t)c * 512 + col]);
    s += psum[(size_t)c * 512 + col];
  }
  rz[col] = m;
  rz[512 + col] = s / (float)NN;
  if (col == 0) rz[1024] = yt[0];
}

// ---------------- fused CSR gather (bf16 in/out), vectorized: O = 4*NT ----------------
template <int NT, bool PRE>
__global__ __launch_bounds__(NT)
void k_gatherv(const int* __restrict__ rowptr, const int* __restrict__ colsrc,
               const float* __restrict__ ecw, const float* __restrict__ dinv,
               const float* __restrict__ dinv2, const u16* __restrict__ xw,
               const float* __restrict__ bias, u16* __restrict__ h) {
  const int O = 4 * NT;
  const int row = blockIdx.x;
  const int tid = threadIdx.x;
  const float dv = dinv[row], dv2 = dinv2[row];
  uint2 u = ((const uint2*)(xw + (size_t)row * O))[tid];
  float a0 = dv2 * bf16lo(u.x), a1 = dv2 * bf16hi(u.x);
  float a2 = dv2 * bf16lo(u.y), a3 = dv2 * bf16hi(u.y);
  if (!PRE) {
    a0 += bias[4 * tid];     a1 += bias[4 * tid + 1];
    a2 += bias[4 * tid + 2]; a3 += bias[4 * tid + 3];
  }
  float c0 = 0.f, c1 = 0.f, c2 = 0.f, c3 = 0.f;

  __shared__ int s_src[NT];
  __shared__ float s_w[NT];
  const int e0 = rowptr[row], e1 = rowptr[row + 1];
  for (int base = e0; base < e1; base += NT) {
    int cnt = min(NT, e1 - base);
    __syncthreads();
    if (tid < cnt) {
      int s = colsrc[base + tid];
      s_src[tid] = s;
      s_w[tid] = dinv[s] * ecw[base + tid] * dv;
    }
    __syncthreads();
    int e = 0;
    for (; e + 2 <= cnt; e += 2) {
      float w0 = s_w[e], w1 = s_w[e + 1];
      uint2 v0 = ((const uint2*)(xw + (size_t)s_src[e] * O))[tid];
      uint2 v1 = ((const uint2*)(xw + (size_t)s_src[e + 1] * O))[tid];
      a0 += w0 * bf16lo(v0.x); a1 += w0 * bf16hi(v0.x);
      a2 += w0 * bf16lo(v0.y); a3 += w0 * bf16hi(v0.y);
      c0 += w1 * bf16lo(v1.x); c1 += w1 * bf16hi(v1.x);
      c2 += w1 * bf16lo(v1.y); c3 += w1 * bf16hi(v1.y);
    }
    if (e < cnt) {
      float w = s_w[e];
      uint2 v = ((const uint2*)(xw + (size_t)s_src[e] * O))[tid];
      a0 += w * bf16lo(v.x); a1 += w * bf16hi(v.x);
      a2 += w * bf16lo(v.y); a3 += w * bf16hi(v.y);
    }
  }
  a0 += c0; a1 += c1; a2 += c2; a3 += c3;

  if (PRE) {
    uint2 o; o.x = pack2(a0, a1); o.y = pack2(a2, a3);
    ((uint2*)(h + (size_t)row * O))[tid] = o;
    return;
  }
  float ss = a0 * a0 + a1 * a1 + a2 * a2 + a3 * a3;
#pragma unroll
  for (int off = 32; off > 0; off >>= 1) ss += __shfl_down(ss, off, 64);
  __shared__ float red[(NT + 63) / 64];
  __shared__ float s_scale;
  if ((tid & 63) == 0) red[tid >> 6] = ss;
  __syncthreads();
  if (tid == 0) {
    float t = 0.f;
#pragma unroll
    for (int i = 0; i < (NT + 63) / 64; ++i) t += red[i];
    s_scale = 1.0f / fmaxf(sqrtf(t), 1e-12f);
  }
  __syncthreads();
  float sc = s_scale;
  uint2 o;
  o.x = pack2(fmaxf(a0 * sc, 0.f), fmaxf(a1 * sc, 0.f));
  o.y = pack2(fmaxf(a2 * sc, 0.f), fmaxf(a3 * sc, 0.f));
  ((uint2*)(h + (size_t)row * O))[tid] = o;
}

// ---------------- rowwise l2norm + relu, bf16 in/out, O=1024 ----------------
__global__ __launch_bounds__(256)
void k_l2relu(const u16* __restrict__ t, u16* __restrict__ h) {
  const int row = blockIdx.x;
  const int tid = threadIdx.x;
  const u32* tr = (const u32*)(t + (size_t)row * 1024);
  u32 u0 = tr[tid], u1 = tr[256 + tid];
  float a0 = bf16lo(u0), a1 = bf16hi(u0), a2 = bf16lo(u1), a3 = bf16hi(u1);
  float ss = a0 * a0 + a1 * a1 + a2 * a2 + a3 * a3;
#pragma unroll
  for (int off = 32; off > 0; off >>= 1) ss += __shfl_down(ss, off, 64);
  __shared__ float red[4];
  __shared__ float s_scale;
  if ((tid & 63) == 0) red[tid >> 6] = ss;
  __syncthreads();
  if (tid == 0) {
    float s = red[0] + red[1] + red[2] + red[3];
    s_scale = 1.0f / fmaxf(sqrtf(s), 1e-12f);
  }
  __syncthreads();
  float sc = s_scale;
  u32* hr = (u32*)(h + (size_t)row * 1024);
  hr[tid]       = pack2(fmaxf(a0 * sc, 0.f), fmaxf(a1 * sc, 0.f));
  hr[256 + tid] = pack2(fmaxf(a2 * sc, 0.f), fmaxf(a3 * sc, 0.f));
}

// ---------------- parallel decoder ----------------
__global__ __launch_bounds__(256)
void k_dec_partial(const float* __restrict__ v, const float* __restrict__ W,
                   float* __restrict__ partial, int Kdim, int Ndim) {
  int b = blockIdx.x;
  int lo = b * DCH;
  float rv[DCH];
#pragma unroll
  for (int j = 0; j < DCH; ++j) rv[j] = (lo + j < Kdim) ? v[lo + j] : 0.f;
  for (int n = threadIdx.x; n < Ndim; n += 256) {
    float s = 0.f;
#pragma unroll
    for (int j = 0; j < DCH; ++j)
      if (lo + j < Kdim) s += rv[j] * W[(size_t)(lo + j) * Ndim + n];
    partial[(size_t)b * Ndim + n] = s;
  }
}

template <int ACT>
__global__ __launch_bounds__(256)
void k_dec_combine(const float* __restrict__ partial, const float* __restrict__ bias,
                   float* __restrict__ out, int Ndim) {
  int n = blockIdx.x * 256 + threadIdx.x;
  if (n >= Ndim) return;
  float s = bias[n];
  for (int b = 0; b < DKB; ++b) s += partial[(size_t)b * Ndim + n];
  out[n] = (ACT == 0) ? fmaxf(s, 0.f) : 1.0f / (1.0f + expf(-s));
}

extern "C" void kernel_launch(void* const* d_in, const int* in_sizes, int n_in,
                              void* d_out, int out_size, void* d_ws, size_t ws_size,
                              hipStream_t stream) {
  const float* x    = (const float*)d_in[0];
  const int*   ei   = (const int*)d_in[1];
  const float* ew   = (const float*)d_in[2];
  const float* beta = (const float*)d_in[3];
  const float* yt   = (const float*)d_in[4];
  const float* eps  = (const float*)d_in[5];
  const float* W1   = (const float*)d_in[6];  const float* b1  = (const float*)d_in[7];
  const float* W2   = (const float*)d_in[8];  const float* b2  = (const float*)d_in[9];
  const float* W3   = (const float*)d_in[10]; const float* b3  = (const float*)d_in[11];
  const float* Wmu  = (const float*)d_in[12]; const float* bmu = (const float*)d_in[13];
  const float* Wlv  = (const float*)d_in[14]; const float* blv = (const float*)d_in[15];
  const float* Wd1  = (const float*)d_in[16]; const float* bd1 = (const float*)d_in[17];
  const float* Wd2  = (const float*)d_in[18]; const float* bd2 = (const float*)d_in[19];

  char* wsb = (char*)d_ws;
  size_t off = 0;
  // 16B-aligned workspace allocs (uint2 / dwordx4 natural alignment)
  auto alloc_f = [&](size_t n) { float* p = (float*)(wsb + off); off += ((n * sizeof(float) + 15) & ~(size_t)15); return p; };
  auto alloc_i = [&](size_t n) { int* p = (int*)(wsb + off); off += ((n * sizeof(int) + 15) & ~(size_t)15); return p; };
  auto alloc_h = [&](size_t n) { u16* p = (u16*)(wsb + off); off += ((n * 2 + 15) & ~(size_t)15); return p; };

  int* counts  = alloc_i(NN);
  int* rowptr  = alloc_i(NN + 1);
  int* cursor  = alloc_i(NN);
  int* colsrc  = alloc_i(EE);
  float* ecw   = alloc_f(EE);
  float* dinv  = alloc_f(NN);
  float* din2  = alloc_f(NN);
  float* pmax  = alloc_f((size_t)MTILES * 512);
  float* psum  = alloc_f((size_t)MTILES * 512);
  float* rz    = alloc_f(1028);
  float* hdec  = alloc_f(1028);
  float* part1 = alloc_f((size_t)DKB * 1025);
  float* part2 = alloc_f((size_t)DKB * 1024);
  u16* W1T  = alloc_h(1024 * 512);
  u16* W2T  = alloc_h(512 * 1024);
  u16* W3T  = alloc_h(256 * 512);
  u16* WmuT = alloc_h(512 * 256);
  u16* WlvT = alloc_h(512 * 256);
  u16* xb   = alloc_h((size_t)MPAD * 512);   // x bf16; later reused as h3 (256)
  u16* aggx = alloc_h((size_t)MPAD * 512);   // pre-aggregated x
  u16* bufT = alloc_h((size_t)MPAD * 1024);  // t1; later z2 (512)
  u16* bufH = alloc_h((size_t)MPAD * 1024);  // h1; later z3 (256)
  u16* h2   = alloc_h((size_t)MPAD * 512);
  u16* h3   = xb;
  u16* z2   = bufT;
  u16* z3   = bufH;

  float* out_f  = (float*)d_out;
  float* mu_out = out_f + 1024;
  float* lv_out = out_f + 1024 + (size_t)NN * 512;

  const int MT = MTILES;

  // ---- casts / transposes ----
  k_f2b2<<<4096, 256, 0, stream>>>(x, xb, NN * 512 / 2);
  k_wt_all<<<5632, 256, 0, stream>>>(W1, W2, W3, Wmu, Wlv, W1T, W2T, W3T, WmuT, WlvT);

  // ---- CSR build + degree norms ----
  k_zeroi<<<(NN + 255) / 256, 256, 0, stream>>>(counts, NN);
  k_count<<<(EE + 255) / 256, 256, 0, stream>>>(ei, counts);
  k_scan<<<1, 256, 0, stream>>>(counts, rowptr, cursor);
  k_fill<<<(EE + 255) / 256, 256, 0, stream>>>(ei, ew, cursor, colsrc, ecw);
  k_degcsr<<<(NN + 255) / 256, 256, 0, stream>>>(rowptr, ecw, dinv, din2);

  // ---- layer 1: aggregate x first (linearity), then GEMM+bias, then l2relu ----
  k_gatherv<128, true><<<NN, 128, 0, stream>>>(rowptr, colsrc, ecw, dinv, din2, xb, nullptr, aggx);
  k_mfma<true, true><<<MT * 8, 256, 0, stream>>>(aggx, W1T, b1, bufT, NN, 512, 1024);
  k_l2relu<<<NN, 256, 0, stream>>>(bufT, bufH);

  // ---- layer 2: GEMM then fused gather+bias+l2relu ----
  k_mfma<true, false><<<MT * 4, 256, 0, stream>>>(bufH, W2T, nullptr, z2, NN, 1024, 512);
  k_gatherv<128, false><<<NN, 128, 0, stream>>>(rowptr, colsrc, ecw, dinv, din2, z2, b2, h2);

  // ---- layer 3 ----
  k_mfma<true, false><<<MT * 2, 256, 0, stream>>>(h2, W3T, nullptr, z3, NN, 512, 256);
  k_gatherv<64, false><<<NN, 64, 0, stream>>>(rowptr, colsrc, ecw, dinv, din2, z3, b3, h3);

  // ---- fused VAE heads + reparameterize + partial pooling (64-wide N tiles) ----
  k_heads<<<MT * 8, 256, 0, stream>>>(h3, WmuT, WlvT, bmu, blv, eps, beta,
                                      mu_out, lv_out, pmax, psum);
  k_zred<<<1, 512, 0, stream>>>(pmax, psum, yt, rz);

  // ---- parallel decoder ----
  k_dec_partial<<<DKB, 256, 0, stream>>>(rz, Wd1, part1, 1025, 1025);
  k_dec_combine<0><<<5, 256, 0, stream>>>(part1, bd1, hdec, 1025);
  k_dec_partial<<<DKB, 256, 0, stream>>>(hdec, Wd2, part2, 1025, 1024);
  k_dec_combine<1><<<4, 256, 0, stream>>>(part2, bd2, out_f, 1024);
}